// Round 6
// baseline (3624.846 us; speedup 1.0000x reference)
//
#include <hip/hip_runtime.h>
#include <hip/hip_bf16.h>
#include <type_traits>

typedef __hip_bfloat16 bf16;

__device__ __forceinline__ float toF(float x) { return x; }
__device__ __forceinline__ float toF(bf16 x) { return __bfloat162float(x); }

__device__ __forceinline__ float waveReduce(float v) {
#pragma unroll
    for (int o = 32; o > 0; o >>= 1) v += __shfl_xor(v, o, 64);
    return v;
}

// twt_X[i,f] = mean_j word_emb[idx[i,j], f]   (L=16 fixed); fp32 in, bf16 out
__global__ void gather_mean_kernel(const int* __restrict__ idx,
                                   const float* __restrict__ emb,
                                   bf16* __restrict__ out, int N, int D) {
    int wave = (blockIdx.x * blockDim.x + threadIdx.x) >> 6;
    int lane = threadIdx.x & 63;
    if (wave >= N) return;
    const int* ip = idx + wave * 16;
    int inds[16];
#pragma unroll
    for (int j = 0; j < 16; ++j) inds[j] = ip[j];
    for (int f = lane; f < D; f += 64) {
        float acc = 0.f;
#pragma unroll
        for (int j = 0; j < 16; ++j) acc += emb[(size_t)inds[j] * D + f];
        out[(size_t)wave * D + f] = __float2bfloat16(acc * (1.0f / 16.0f));
    }
}

// C[M,N] = A[M,K] @ W[K,N], fp32 accum; fused f_src = C_row . a[:N], f_dst = C_row . a[N:]
template <typename AT, int N>
__global__ void gemm_rowwave_kernel(const AT* __restrict__ A, const float* __restrict__ W,
                                    const float* __restrict__ a,
                                    float* __restrict__ C,
                                    float* __restrict__ fsrc, float* __restrict__ fdst,
                                    int M, int K) {
    int wave = (blockIdx.x * blockDim.x + threadIdx.x) >> 6;
    int lane = threadIdx.x & 63;
    if (wave >= M) return;
    constexpr int P = N / 64;
    float acc[P];
#pragma unroll
    for (int p = 0; p < P; ++p) acc[p] = 0.f;
    const AT* Arow = A + (size_t)wave * K;
    for (int k0 = 0; k0 < K; k0 += 64) {
        int kk = k0 + lane;
        float av = (kk < K) ? toF(Arow[kk]) : 0.f;
        int kmax = min(64, K - k0);
        for (int j = 0; j < kmax; ++j) {
            float aval = __shfl(av, j, 64);
#pragma unroll
            for (int p = 0; p < P; ++p)
                acc[p] += aval * W[(size_t)(k0 + j) * N + lane + 64 * p];
        }
    }
#pragma unroll
    for (int p = 0; p < P; ++p) C[(size_t)wave * N + lane + 64 * p] = acc[p];
    float fs = 0.f, fd = 0.f;
#pragma unroll
    for (int p = 0; p < P; ++p) {
        fs += acc[p] * a[lane + 64 * p];
        fd += acc[p] * a[N + lane + 64 * p];
    }
    fs = waveReduce(fs);
    fd = waveReduce(fd);
    if (lane == 0) { fsrc[wave] = fs; fdst[wave] = fd; }
}

// per edge: e = exp(-leakyrelu(fsrc[row]+fdst[col], 0.2)); num[row,:] += e*h[col,:]; denom[row]+=e
template <int N>
__global__ void edge_scatter_kernel(const int* __restrict__ row, const int* __restrict__ col,
                                    const float* __restrict__ fsrc, const float* __restrict__ fdst,
                                    const float* __restrict__ h,
                                    float* __restrict__ num, float* __restrict__ denom, int E) {
    int wave = (blockIdx.x * blockDim.x + threadIdx.x) >> 6;
    int lane = threadIdx.x & 63;
    if (wave >= E) return;
    int r = row[wave], c = col[wave];
    float f = fsrc[r] + fdst[c];
    float lr = f >= 0.f ? f : 0.2f * f;
    float e = expf(-lr);
    constexpr int P = N / 64;
#pragma unroll
    for (int p = 0; p < P; ++p)
        atomicAdd(&num[(size_t)r * N + lane + 64 * p], e * h[(size_t)c * N + lane + 64 * p]);
    if (lane == 0) atomicAdd(&denom[r], e);
}

// out = elu(num / (denom + 1e-16)), in place
__global__ void finalize_kernel(float* __restrict__ num, const float* __restrict__ denom,
                                int total, int D) {
    int i = blockIdx.x * blockDim.x + threadIdx.x;
    if (i >= total) return;
    int r = i / D;
    float v = num[i] / (denom[r] + 1e-16f);
    num[i] = v > 0.f ? v : expm1f(v);
}

// attsum += sum_rows( sum_j tanh(X@Wm)[r,j] * proj[j] )   (J = 128 fixed)
__global__ void att_reduce_kernel(const float* __restrict__ X, const float* __restrict__ Wm,
                                  const float* __restrict__ proj, float* __restrict__ attsum,
                                  int Nrows) {
    int wave = (blockIdx.x * blockDim.x + threadIdx.x) >> 6;
    int lane = threadIdx.x & 63;
    if (wave >= Nrows) return;
    const float* xr = X + (size_t)wave * 128;
    float acc0 = 0.f, acc1 = 0.f;
    for (int k0 = 0; k0 < 128; k0 += 64) {
        float xv = xr[k0 + lane];
        for (int j = 0; j < 64; ++j) {
            float x = __shfl(xv, j, 64);
            acc0 += x * Wm[(size_t)(k0 + j) * 128 + lane];
            acc1 += x * Wm[(size_t)(k0 + j) * 128 + lane + 64];
        }
    }
    float s = tanhf(acc0) * proj[lane] + tanhf(acc1) * proj[lane + 64];
    s = waveReduce(s);
    if (lane == 0) atomicAdd(attsum, s);
}

// NOTE: output is fp32 (reference output dtype is float32) — writing bf16 here was
// the R2–R5 failure mode (half-filled float buffer => absmax exactly max|ref|).
__global__ void final_kernel(const float* __restrict__ twX, const float* __restrict__ tuX,
                             const int* __restrict__ twi, const int* __restrict__ tui,
                             const float* __restrict__ attsum,
                             const float* __restrict__ outW, const float* __restrict__ outb,
                             float* __restrict__ out, int B, float invNtw, float invNuv) {
    int wave = (blockIdx.x * blockDim.x + threadIdx.x) >> 6;
    int lane = threadIdx.x & 63;
    if (wave >= B) return;
    float z0 = attsum[0] * invNtw, z1 = attsum[1] * invNuv;
    float m = fmaxf(z0, z1);
    float e0 = expf(z0 - m), e1 = expf(z1 - m);
    float a0 = e0 / (e0 + e1), a1 = e1 / (e0 + e1);
    int ti = twi[wave], ui = tui[wave];
    float l0 = 0.f, l1 = 0.f;
#pragma unroll
    for (int p = 0; p < 2; ++p) {
        int j = lane + 64 * p;
        float feat = a0 * twX[(size_t)ti * 128 + j] + a1 * tuX[(size_t)ui * 128 + j];
        l0 += feat * outW[j];
        l1 += feat * outW[128 + j];
    }
    l0 = waveReduce(l0);
    l1 = waveReduce(l1);
    if (lane == 0) {
        l0 += outb[0];
        l1 += outb[1];
        float mm = fmaxf(l0, l1);
        float lse = mm + logf(expf(l0 - mm) + expf(l1 - mm));
        out[wave * 2 + 0] = l0 - lse;
        out[wave * 2 + 1] = l1 - lse;
    }
}

extern "C" void kernel_launch(void* const* d_in, const int* in_sizes, int n_in,
                              void* d_out, int out_size, void* d_ws, size_t ws_size,
                              hipStream_t stream) {
    const int* features_index = (const int*)d_in[0];
    const int* tw_edges = (const int*)d_in[1];
    const int* ut_edges = (const int*)d_in[2];
    const int* tw_gidx = (const int*)d_in[3];
    const int* ut_gidx = (const int*)d_in[4];
    const float* word_emb = (const float*)d_in[5];
    const float* user_emb = (const float*)d_in[6];
    const float* tw_W1 = (const float*)d_in[7];
    const float* tw_a1 = (const float*)d_in[8];
    const float* tw_W2 = (const float*)d_in[9];
    const float* tw_a2 = (const float*)d_in[10];
    const float* tu_W1 = (const float*)d_in[11];
    const float* tu_a1 = (const float*)d_in[12];
    const float* tu_W2 = (const float*)d_in[13];
    const float* tu_a2 = (const float*)d_in[14];
    const float* weight_W = (const float*)d_in[15];
    const float* weight_proj = (const float*)d_in[16];
    const float* out_W = (const float*)d_in[17];
    const float* out_b = (const float*)d_in[18];

    const int HID = in_sizes[8] / 2;            // 64
    const int NFEAT = in_sizes[7] / HID;        // 300
    const int E = in_sizes[1] / 2;              // 800000
    const int NTW = in_sizes[0] / 16;           // 50000
    const int UV = in_sizes[6] / NFEAT;         // 50000
    const int B = in_sizes[3];                  // 4096
    const int Nmax = NTW > UV ? NTW : UV;

    char* ws = (char*)d_ws;
    size_t off = 0;
    auto carve = [&](size_t bytes) -> void* {
        void* p = ws + off;
        off += (bytes + 255) & ~(size_t)255;
        return p;
    };
    bf16* twtX = (bf16*)carve((size_t)NTW * NFEAT * sizeof(bf16));
    float* bufH = (float*)carve((size_t)Nmax * 128 * sizeof(float));   // h1 (N x 64) / h2 (N x 128)
    float* num1 = (float*)carve((size_t)Nmax * 64 * sizeof(float));    // layer-1 accum -> out1
    float* twXf = (float*)carve((size_t)NTW * 128 * sizeof(float));
    float* tuXf = (float*)carve((size_t)UV * 128 * sizeof(float));
    float* f_s = (float*)carve((size_t)Nmax * sizeof(float));
    float* f_d = (float*)carve((size_t)Nmax * sizeof(float));
    float* denom = (float*)carve((size_t)Nmax * sizeof(float));
    float* attsum = (float*)carve(256);
    (void)ws_size; (void)n_in; (void)out_size;

    // tweet features
    gather_mean_kernel<<<(NTW + 3) / 4, 256, 0, stream>>>(features_index, word_emb, twtX, NTW, NFEAT);

    auto run_branch = [&](auto Xb, const int* edges, const float* W1, const float* a1,
                          const float* W2, const float* a2, float* Xfinal, int N) {
        using AT = typename std::remove_const<typename std::remove_pointer<decltype(Xb)>::type>::type;
        const int* row = edges;
        const int* col = edges + E;
        int gN = (N + 3) / 4;
        int gE = (E + 3) / 4;
        // layer 1 (d=64)
        gemm_rowwave_kernel<AT, 64><<<gN, 256, 0, stream>>>(Xb, W1, a1, bufH, f_s, f_d, N, NFEAT);
        hipMemsetAsync(num1, 0, (size_t)N * 64 * sizeof(float), stream);
        hipMemsetAsync(denom, 0, (size_t)N * sizeof(float), stream);
        edge_scatter_kernel<64><<<gE, 256, 0, stream>>>(row, col, f_s, f_d, bufH, num1, denom, E);
        finalize_kernel<<<((N * 64) + 255) / 256, 256, 0, stream>>>(num1, denom, N * 64, 64);
        // layer 2 (d=128)
        gemm_rowwave_kernel<float, 128><<<gN, 256, 0, stream>>>(num1, W2, a2, bufH, f_s, f_d, N, HID);
        hipMemsetAsync(Xfinal, 0, (size_t)N * 128 * sizeof(float), stream);
        hipMemsetAsync(denom, 0, (size_t)N * sizeof(float), stream);
        edge_scatter_kernel<128><<<gE, 256, 0, stream>>>(row, col, f_s, f_d, bufH, Xfinal, denom, E);
        finalize_kernel<<<((N * 128) + 255) / 256, 256, 0, stream>>>(Xfinal, denom, N * 128, 128);
    };

    run_branch((const bf16*)twtX, tw_edges, tw_W1, tw_a1, tw_W2, tw_a2, twXf, NTW);
    run_branch((const float*)user_emb, ut_edges, tu_W1, tu_a1, tu_W2, tu_a2, tuXf, UV);

    // fusion attention
    hipMemsetAsync(attsum, 0, 2 * sizeof(float), stream);
    att_reduce_kernel<<<(NTW + 3) / 4, 256, 0, stream>>>(twXf, weight_W, weight_proj, attsum + 0, NTW);
    att_reduce_kernel<<<(UV + 3) / 4, 256, 0, stream>>>(tuXf, weight_W, weight_proj, attsum + 1, UV);

    final_kernel<<<(B + 3) / 4, 256, 0, stream>>>(twXf, tuXf, tw_gidx, ut_gidx, attsum,
                                                  out_W, out_b, (float*)d_out, B,
                                                  1.0f / (float)NTW, 1.0f / (float)UV);
}

// Round 7
// 1931.355 us; speedup vs baseline: 1.8768x; 1.8768x over previous
//
#include <hip/hip_runtime.h>
#include <hip/hip_bf16.h>

typedef __hip_bfloat16 bf16;

__device__ __forceinline__ float toF(float x) { return x; }
__device__ __forceinline__ float toF(bf16 x) { return __bfloat162float(x); }

__device__ __forceinline__ float waveReduce(float v) {
#pragma unroll
    for (int o = 32; o > 0; o >>= 1) v += __shfl_xor(v, o, 64);
    return v;
}

// twt_X[i,:] = mean_j word_emb[idx[i,j], :]; 300 floats = 75 float4; bf16 out (ws budget)
__global__ void gather_mean_kernel(const int* __restrict__ idx,
                                   const float4* __restrict__ emb,
                                   bf16* __restrict__ out, int N) {
    int wave = (blockIdx.x * blockDim.x + threadIdx.x) >> 6;
    int lane = threadIdx.x & 63;
    if (wave >= N) return;
    const int* ip = idx + wave * 16;
    int inds[16];
#pragma unroll
    for (int j = 0; j < 16; ++j) inds[j] = ip[j];
    for (int f = lane; f < 75; f += 64) {
        float4 acc = {0.f, 0.f, 0.f, 0.f};
#pragma unroll
        for (int j = 0; j < 16; ++j) {
            float4 v = emb[(size_t)inds[j] * 75 + f];
            acc.x += v.x; acc.y += v.y; acc.z += v.z; acc.w += v.w;
        }
        bf16* o = out + (size_t)wave * 300 + f * 4;
        o[0] = __float2bfloat16(acc.x * 0.0625f);
        o[1] = __float2bfloat16(acc.y * 0.0625f);
        o[2] = __float2bfloat16(acc.z * 0.0625f);
        o[3] = __float2bfloat16(acc.w * 0.0625f);
    }
}

// Layer-1 GEMM: C[M,64] = X[M,300] @ W[300,64]; LDS-tiled, 16 rows/block.
// Fused fsrc = C_row.a[0:64], fdst = C_row.a[64:128].
#define KC1 100
template <typename XT>
__global__ __launch_bounds__(256) void gemm_l1(const XT* __restrict__ X,
                                               const float* __restrict__ W,
                                               const float* __restrict__ a,
                                               float* __restrict__ C,
                                               float* __restrict__ fs, float* __restrict__ fd,
                                               int M) {
    __shared__ float Ws[KC1 * 64];   // 25.6 KB
    __shared__ float Xs[16 * KC1];   // 6.4 KB
    int t = threadIdx.x;
    int c = t & 63;        // lane = output col
    int rg = t >> 6;       // wave id 0..3 -> row group
    int row0 = blockIdx.x * 16;
    float acc[4] = {0.f, 0.f, 0.f, 0.f};
    for (int k0 = 0; k0 < 300; k0 += KC1) {
        for (int e = t; e < KC1 * 64; e += 256)
            Ws[e] = W[(size_t)(k0 + (e >> 6)) * 64 + (e & 63)];
        for (int e = t; e < 16 * KC1; e += 256) {
            int r = e / KC1, kk = e - r * KC1;
            int gr = row0 + r;
            Xs[e] = (gr < M) ? toF(X[(size_t)gr * 300 + k0 + kk]) : 0.f;
        }
        __syncthreads();
        for (int k = 0; k < KC1; ++k) {
            float wv = Ws[k * 64 + c];
#pragma unroll
            for (int i = 0; i < 4; ++i)
                acc[i] += Xs[(rg * 4 + i) * KC1 + k] * wv;   // broadcast within wave
        }
        __syncthreads();
    }
#pragma unroll
    for (int i = 0; i < 4; ++i) {
        int gr = row0 + rg * 4 + i;
        if (gr < M) C[(size_t)gr * 64 + c] = acc[i];
    }
    float a0 = a[c], a1 = a[64 + c];
#pragma unroll
    for (int i = 0; i < 4; ++i) {
        float p = waveReduce(acc[i] * a0);
        float q = waveReduce(acc[i] * a1);
        int gr = row0 + rg * 4 + i;
        if (c == 0 && gr < M) { fs[gr] = p; fd[gr] = q; }
    }
}

// Layer-2 GEMM: C[M,128] = H[M,64] @ W[64,128]; whole W in LDS; 16 rows/block.
__global__ __launch_bounds__(256) void gemm_l2(const float* __restrict__ H,
                                               const float* __restrict__ W,
                                               const float* __restrict__ a,
                                               float* __restrict__ C,
                                               float* __restrict__ fs, float* __restrict__ fd,
                                               int M) {
    __shared__ float Ws[64 * 128];        // 32 KB
    __shared__ float Xs[16 * 64];         // 4 KB
    __shared__ float fpart[2][16][2];
    int t = threadIdx.x;
    int c = t & 127;       // output col
    int rg = t >> 7;       // 0..1 -> row group (8 rows each)
    int half = (t >> 6) & 1;
    int row0 = blockIdx.x * 16;
    for (int e = t; e < 64 * 128; e += 256) Ws[e] = W[e];
    for (int e = t; e < 16 * 64; e += 256) {
        int gr = row0 + (e >> 6);
        Xs[e] = (gr < M) ? H[(size_t)gr * 64 + (e & 63)] : 0.f;
    }
    __syncthreads();
    float acc[8] = {0.f, 0.f, 0.f, 0.f, 0.f, 0.f, 0.f, 0.f};
    for (int k = 0; k < 64; ++k) {
        float wv = Ws[k * 128 + c];
#pragma unroll
        for (int i = 0; i < 8; ++i)
            acc[i] += Xs[(rg * 8 + i) * 64 + k] * wv;
    }
    float a0 = a[c], a1 = a[128 + c];
#pragma unroll
    for (int i = 0; i < 8; ++i) {
        int gr = row0 + rg * 8 + i;
        if (gr < M) C[(size_t)gr * 128 + c] = acc[i];
        float p = waveReduce(acc[i] * a0);
        float q = waveReduce(acc[i] * a1);
        if ((t & 63) == 0) { fpart[half][rg * 8 + i][0] = p; fpart[half][rg * 8 + i][1] = q; }
    }
    __syncthreads();
    if (t < 16) {
        int gr = row0 + t;
        if (gr < M) {
            fs[gr] = fpart[0][t][0] + fpart[1][t][0];
            fd[gr] = fpart[0][t][1] + fpart[1][t][1];
        }
    }
}

// attsum += sum_r (tanh(X@W)[r,:] . proj); X rows 128 wide; LDS-tiled.
#define KCA 64
__global__ __launch_bounds__(256) void att_tiled(const float* __restrict__ X,
                                                 const float* __restrict__ W,
                                                 const float* __restrict__ proj,
                                                 float* __restrict__ attsum, int M) {
    __shared__ float Ws[KCA * 128];   // 32 KB
    __shared__ float Xs[16 * KCA];    // 4 KB
    __shared__ float bs[4];
    int t = threadIdx.x;
    int c = t & 127;
    int rg = t >> 7;
    int row0 = blockIdx.x * 16;
    float acc[8] = {0.f, 0.f, 0.f, 0.f, 0.f, 0.f, 0.f, 0.f};
    for (int k0 = 0; k0 < 128; k0 += KCA) {
        for (int e = t; e < KCA * 128; e += 256)
            Ws[e] = W[(size_t)(k0 + (e >> 7)) * 128 + (e & 127)];
        for (int e = t; e < 16 * KCA; e += 256) {
            int gr = row0 + (e / KCA);
            Xs[e] = (gr < M) ? X[(size_t)gr * 128 + k0 + (e % KCA)] : 0.f;
        }
        __syncthreads();
        for (int k = 0; k < KCA; ++k) {
            float wv = Ws[k * 128 + c];
#pragma unroll
            for (int i = 0; i < 8; ++i)
                acc[i] += Xs[(rg * 8 + i) * KCA + k] * wv;
        }
        __syncthreads();
    }
    float pj = proj[c];
    float s = 0.f;
#pragma unroll
    for (int i = 0; i < 8; ++i) {
        int gr = row0 + rg * 8 + i;
        if (gr < M) s += tanhf(acc[i]) * pj;
    }
    s = waveReduce(s);
    if ((t & 63) == 0) bs[t >> 6] = s;
    __syncthreads();
    if (t == 0) atomicAdd(attsum, bs[0] + bs[1] + bs[2] + bs[3]);
}

// per edge: e = exp(-leakyrelu(fsrc[row]+fdst[col], 0.2)); num[row,:] += e*h[col,:]; denom[row]+=e
template <int N>
__global__ void edge_scatter_kernel(const int* __restrict__ row, const int* __restrict__ col,
                                    const float* __restrict__ fsrc, const float* __restrict__ fdst,
                                    const float* __restrict__ h,
                                    float* __restrict__ num, float* __restrict__ denom, int E) {
    int wave = (blockIdx.x * blockDim.x + threadIdx.x) >> 6;
    int lane = threadIdx.x & 63;
    if (wave >= E) return;
    int r = row[wave], c = col[wave];
    float f = fsrc[r] + fdst[c];
    float lr = f >= 0.f ? f : 0.2f * f;
    float e = expf(-lr);
    constexpr int P = N / 64;
#pragma unroll
    for (int p = 0; p < P; ++p)
        atomicAdd(&num[(size_t)r * N + lane + 64 * p], e * h[(size_t)c * N + lane + 64 * p]);
    if (lane == 0) atomicAdd(&denom[r], e);
}

__global__ void finalize_kernel(float* __restrict__ num, const float* __restrict__ denom,
                                int total, int D) {
    int i = blockIdx.x * blockDim.x + threadIdx.x;
    if (i >= total) return;
    int r = i / D;
    float v = num[i] / (denom[r] + 1e-16f);
    num[i] = v > 0.f ? v : expm1f(v);
}

// output fp32 (proven R6)
__global__ void final_kernel(const float* __restrict__ twX, const float* __restrict__ tuX,
                             const int* __restrict__ twi, const int* __restrict__ tui,
                             const float* __restrict__ attsum,
                             const float* __restrict__ outW, const float* __restrict__ outb,
                             float* __restrict__ out, int B, float invNtw, float invNuv) {
    int wave = (blockIdx.x * blockDim.x + threadIdx.x) >> 6;
    int lane = threadIdx.x & 63;
    if (wave >= B) return;
    float z0 = attsum[0] * invNtw, z1 = attsum[1] * invNuv;
    float m = fmaxf(z0, z1);
    float e0 = expf(z0 - m), e1 = expf(z1 - m);
    float a0 = e0 / (e0 + e1), a1 = e1 / (e0 + e1);
    int ti = twi[wave], ui = tui[wave];
    float l0 = 0.f, l1 = 0.f;
#pragma unroll
    for (int p = 0; p < 2; ++p) {
        int j = lane + 64 * p;
        float feat = a0 * twX[(size_t)ti * 128 + j] + a1 * tuX[(size_t)ui * 128 + j];
        l0 += feat * outW[j];
        l1 += feat * outW[128 + j];
    }
    l0 = waveReduce(l0);
    l1 = waveReduce(l1);
    if (lane == 0) {
        l0 += outb[0];
        l1 += outb[1];
        float mm = fmaxf(l0, l1);
        float lse = mm + logf(expf(l0 - mm) + expf(l1 - mm));
        out[wave * 2 + 0] = l0 - lse;
        out[wave * 2 + 1] = l1 - lse;
    }
}

extern "C" void kernel_launch(void* const* d_in, const int* in_sizes, int n_in,
                              void* d_out, int out_size, void* d_ws, size_t ws_size,
                              hipStream_t stream) {
    const int* features_index = (const int*)d_in[0];
    const int* tw_edges = (const int*)d_in[1];
    const int* ut_edges = (const int*)d_in[2];
    const int* tw_gidx = (const int*)d_in[3];
    const int* ut_gidx = (const int*)d_in[4];
    const float* word_emb = (const float*)d_in[5];
    const float* user_emb = (const float*)d_in[6];
    const float* tw_W1 = (const float*)d_in[7];
    const float* tw_a1 = (const float*)d_in[8];
    const float* tw_W2 = (const float*)d_in[9];
    const float* tw_a2 = (const float*)d_in[10];
    const float* tu_W1 = (const float*)d_in[11];
    const float* tu_a1 = (const float*)d_in[12];
    const float* tu_W2 = (const float*)d_in[13];
    const float* tu_a2 = (const float*)d_in[14];
    const float* weight_W = (const float*)d_in[15];
    const float* weight_proj = (const float*)d_in[16];
    const float* out_W = (const float*)d_in[17];
    const float* out_b = (const float*)d_in[18];

    const int E = in_sizes[1] / 2;              // 800000
    const int NTW = in_sizes[0] / 16;           // 50000
    const int UV = in_sizes[6] / 300;           // 50000
    const int B = in_sizes[3];                  // 4096
    const int Nmax = NTW > UV ? NTW : UV;

    char* ws = (char*)d_ws;
    size_t off = 0;
    auto carve = [&](size_t bytes) -> void* {
        void* p = ws + off;
        off += (bytes + 255) & ~(size_t)255;
        return p;
    };
    bf16* twtX = (bf16*)carve((size_t)NTW * 300 * sizeof(bf16));
    float* bufH = (float*)carve((size_t)Nmax * 128 * sizeof(float));
    float* num1 = (float*)carve((size_t)Nmax * 64 * sizeof(float));
    float* twXf = (float*)carve((size_t)NTW * 128 * sizeof(float));
    float* tuXf = (float*)carve((size_t)UV * 128 * sizeof(float));
    float* f_s = (float*)carve((size_t)Nmax * sizeof(float));
    float* f_d = (float*)carve((size_t)Nmax * sizeof(float));
    float* denom = (float*)carve((size_t)Nmax * sizeof(float));
    float* attsum = (float*)carve(256);
    (void)ws_size; (void)n_in; (void)out_size;

    gather_mean_kernel<<<(NTW + 3) / 4, 256, 0, stream>>>(features_index, (const float4*)word_emb,
                                                          twtX, NTW);

    auto run_branch = [&](auto Xb, const int* edges, const float* W1, const float* a1,
                          const float* W2, const float* a2, float* Xfinal, int N) {
        const int* row = edges;
        const int* col = edges + E;
        int gT = (N + 15) / 16;   // tiled GEMM blocks
        int gE = (E + 3) / 4;
        gemm_l1<<<gT, 256, 0, stream>>>(Xb, W1, a1, bufH, f_s, f_d, N);
        hipMemsetAsync(num1, 0, (size_t)N * 64 * sizeof(float), stream);
        hipMemsetAsync(denom, 0, (size_t)N * sizeof(float), stream);
        edge_scatter_kernel<64><<<gE, 256, 0, stream>>>(row, col, f_s, f_d, bufH, num1, denom, E);
        finalize_kernel<<<((N * 64) + 255) / 256, 256, 0, stream>>>(num1, denom, N * 64, 64);
        gemm_l2<<<gT, 256, 0, stream>>>(num1, W2, a2, bufH, f_s, f_d, N);
        hipMemsetAsync(Xfinal, 0, (size_t)N * 128 * sizeof(float), stream);
        hipMemsetAsync(denom, 0, (size_t)N * sizeof(float), stream);
        edge_scatter_kernel<128><<<gE, 256, 0, stream>>>(row, col, f_s, f_d, bufH, Xfinal, denom, E);
        finalize_kernel<<<((N * 128) + 255) / 256, 256, 0, stream>>>(Xfinal, denom, N * 128, 128);
    };

    run_branch((const bf16*)twtX, tw_edges, tw_W1, tw_a1, tw_W2, tw_a2, twXf, NTW);
    run_branch((const float*)user_emb, ut_edges, tu_W1, tu_a1, tu_W2, tu_a2, tuXf, UV);

    hipMemsetAsync(attsum, 0, 2 * sizeof(float), stream);
    att_tiled<<<(NTW + 15) / 16, 256, 0, stream>>>(twXf, weight_W, weight_proj, attsum + 0, NTW);
    att_tiled<<<(UV + 15) / 16, 256, 0, stream>>>(tuXf, weight_W, weight_proj, attsum + 1, UV);

    final_kernel<<<(B + 3) / 4, 256, 0, stream>>>(twXf, tuXf, tw_gidx, ut_gidx, attsum,
                                                  out_W, out_b, (float*)d_out, B,
                                                  1.0f / (float)NTW, 1.0f / (float)UV);
}

// Round 8
// 1414.924 us; speedup vs baseline: 2.5619x; 1.3650x over previous
//
#include <hip/hip_runtime.h>
#include <hip/hip_bf16.h>

typedef __hip_bfloat16 bf16;

__device__ __forceinline__ float toF(float x) { return x; }
__device__ __forceinline__ float toF(bf16 x) { return __bfloat162float(x); }

__device__ __forceinline__ float waveReduce(float v) {
#pragma unroll
    for (int o = 32; o > 0; o >>= 1) v += __shfl_xor(v, o, 64);
    return v;
}

// ---------------- feature prep ----------------
__global__ void gather_mean_kernel(const int* __restrict__ idx,
                                   const float4* __restrict__ emb,
                                   bf16* __restrict__ out, int N) {
    int wave = (blockIdx.x * blockDim.x + threadIdx.x) >> 6;
    int lane = threadIdx.x & 63;
    if (wave >= N) return;
    const int* ip = idx + wave * 16;
    int inds[16];
#pragma unroll
    for (int j = 0; j < 16; ++j) inds[j] = ip[j];
    for (int f = lane; f < 75; f += 64) {
        float4 acc = {0.f, 0.f, 0.f, 0.f};
#pragma unroll
        for (int j = 0; j < 16; ++j) {
            float4 v = emb[(size_t)inds[j] * 75 + f];
            acc.x += v.x; acc.y += v.y; acc.z += v.z; acc.w += v.w;
        }
        bf16* o = out + (size_t)wave * 300 + f * 4;
        o[0] = __float2bfloat16(acc.x * 0.0625f);
        o[1] = __float2bfloat16(acc.y * 0.0625f);
        o[2] = __float2bfloat16(acc.z * 0.0625f);
        o[3] = __float2bfloat16(acc.w * 0.0625f);
    }
}

// ---------------- GEMMs (unchanged from R7) ----------------
#define KC1 100
template <typename XT>
__global__ __launch_bounds__(256) void gemm_l1(const XT* __restrict__ X,
                                               const float* __restrict__ W,
                                               const float* __restrict__ a,
                                               float* __restrict__ C,
                                               float* __restrict__ fs, float* __restrict__ fd,
                                               int M) {
    __shared__ float Ws[KC1 * 64];
    __shared__ float Xs[16 * KC1];
    int t = threadIdx.x;
    int c = t & 63;
    int rg = t >> 6;
    int row0 = blockIdx.x * 16;
    float acc[4] = {0.f, 0.f, 0.f, 0.f};
    for (int k0 = 0; k0 < 300; k0 += KC1) {
        for (int e = t; e < KC1 * 64; e += 256)
            Ws[e] = W[(size_t)(k0 + (e >> 6)) * 64 + (e & 63)];
        for (int e = t; e < 16 * KC1; e += 256) {
            int r = e / KC1, kk = e - r * KC1;
            int gr = row0 + r;
            Xs[e] = (gr < M) ? toF(X[(size_t)gr * 300 + k0 + kk]) : 0.f;
        }
        __syncthreads();
        for (int k = 0; k < KC1; ++k) {
            float wv = Ws[k * 64 + c];
#pragma unroll
            for (int i = 0; i < 4; ++i)
                acc[i] += Xs[(rg * 4 + i) * KC1 + k] * wv;
        }
        __syncthreads();
    }
#pragma unroll
    for (int i = 0; i < 4; ++i) {
        int gr = row0 + rg * 4 + i;
        if (gr < M) C[(size_t)gr * 64 + c] = acc[i];
    }
    float a0 = a[c], a1 = a[64 + c];
#pragma unroll
    for (int i = 0; i < 4; ++i) {
        float p = waveReduce(acc[i] * a0);
        float q = waveReduce(acc[i] * a1);
        int gr = row0 + rg * 4 + i;
        if (c == 0 && gr < M) { fs[gr] = p; fd[gr] = q; }
    }
}

__global__ __launch_bounds__(256) void gemm_l2(const float* __restrict__ H,
                                               const float* __restrict__ W,
                                               const float* __restrict__ a,
                                               float* __restrict__ C,
                                               float* __restrict__ fs, float* __restrict__ fd,
                                               int M) {
    __shared__ float Ws[64 * 128];
    __shared__ float Xs[16 * 64];
    __shared__ float fpart[2][16][2];
    int t = threadIdx.x;
    int c = t & 127;
    int rg = t >> 7;
    int half = (t >> 6) & 1;
    int row0 = blockIdx.x * 16;
    for (int e = t; e < 64 * 128; e += 256) Ws[e] = W[e];
    for (int e = t; e < 16 * 64; e += 256) {
        int gr = row0 + (e >> 6);
        Xs[e] = (gr < M) ? H[(size_t)gr * 64 + (e & 63)] : 0.f;
    }
    __syncthreads();
    float acc[8] = {0.f, 0.f, 0.f, 0.f, 0.f, 0.f, 0.f, 0.f};
    for (int k = 0; k < 64; ++k) {
        float wv = Ws[k * 128 + c];
#pragma unroll
        for (int i = 0; i < 8; ++i)
            acc[i] += Xs[(rg * 8 + i) * 64 + k] * wv;
    }
    float a0 = a[c], a1 = a[128 + c];
#pragma unroll
    for (int i = 0; i < 8; ++i) {
        int gr = row0 + rg * 8 + i;
        if (gr < M) C[(size_t)gr * 128 + c] = acc[i];
        float p = waveReduce(acc[i] * a0);
        float q = waveReduce(acc[i] * a1);
        if ((t & 63) == 0) { fpart[half][rg * 8 + i][0] = p; fpart[half][rg * 8 + i][1] = q; }
    }
    __syncthreads();
    if (t < 16) {
        int gr = row0 + t;
        if (gr < M) {
            fs[gr] = fpart[0][t][0] + fpart[1][t][0];
            fd[gr] = fpart[0][t][1] + fpart[1][t][1];
        }
    }
}

#define KCA 64
__global__ __launch_bounds__(256) void att_tiled(const float* __restrict__ X,
                                                 const float* __restrict__ W,
                                                 const float* __restrict__ proj,
                                                 float* __restrict__ attsum, int M) {
    __shared__ float Ws[KCA * 128];
    __shared__ float Xs[16 * KCA];
    __shared__ float bs[4];
    int t = threadIdx.x;
    int c = t & 127;
    int rg = t >> 7;
    int row0 = blockIdx.x * 16;
    float acc[8] = {0.f, 0.f, 0.f, 0.f, 0.f, 0.f, 0.f, 0.f};
    for (int k0 = 0; k0 < 128; k0 += KCA) {
        for (int e = t; e < KCA * 128; e += 256)
            Ws[e] = W[(size_t)(k0 + (e >> 7)) * 128 + (e & 127)];
        for (int e = t; e < 16 * KCA; e += 256) {
            int gr = row0 + (e / KCA);
            Xs[e] = (gr < M) ? X[(size_t)gr * 128 + k0 + (e % KCA)] : 0.f;
        }
        __syncthreads();
        for (int k = 0; k < KCA; ++k) {
            float wv = Ws[k * 128 + c];
#pragma unroll
            for (int i = 0; i < 8; ++i)
                acc[i] += Xs[(rg * 8 + i) * KCA + k] * wv;
        }
        __syncthreads();
    }
    float pj = proj[c];
    float s = 0.f;
#pragma unroll
    for (int i = 0; i < 8; ++i) {
        int gr = row0 + rg * 8 + i;
        if (gr < M) s += tanhf(acc[i]) * pj;
    }
    s = waveReduce(s);
    if ((t & 63) == 0) bs[t >> 6] = s;
    __syncthreads();
    if (t == 0) atomicAdd(attsum, bs[0] + bs[1] + bs[2] + bs[3]);
}

// ---------------- CSR build ----------------
__global__ void zero_int_kernel(int* p, int n) {
    int i = blockIdx.x * blockDim.x + threadIdx.x;
    if (i < n) p[i] = 0;
}

__global__ void count_kernel(const int* __restrict__ row, int* __restrict__ deg, int E) {
    int i = blockIdx.x * blockDim.x + threadIdx.x;
    if (i < E) atomicAdd(&deg[row[i]], 1);
}

// single-block exclusive scan: deg[N] -> rowptr[N+1] and cursor[N]
__global__ __launch_bounds__(1024) void scan_kernel(const int* __restrict__ deg,
                                                    int* __restrict__ rowptr,
                                                    int* __restrict__ cursor, int N) {
    __shared__ int part[1024];
    int t = threadIdx.x;
    int chunk = (N + 1023) >> 10;
    int s = t * chunk;
    int e = s + chunk; if (e > N) e = N;
    int sum = 0;
    for (int i = s; i < e; ++i) sum += deg[i];
    part[t] = sum;
    __syncthreads();
    for (int off = 1; off < 1024; off <<= 1) {
        int v = (t >= off) ? part[t - off] : 0;
        __syncthreads();
        part[t] += v;
        __syncthreads();
    }
    int run = (t == 0) ? 0 : part[t - 1];
    for (int i = s; i < e; ++i) {
        rowptr[i] = run;
        cursor[i] = run;
        run += deg[i];
    }
    if (t == 1023) rowptr[N] = part[1023];
}

__global__ void scatter_kernel(const int* __restrict__ row, const int* __restrict__ col,
                               int* __restrict__ cursor, int* __restrict__ ecol, int E) {
    int i = blockIdx.x * blockDim.x + threadIdx.x;
    if (i >= E) return;
    int p = atomicAdd(&cursor[row[i]], 1);
    ecol[p] = col[i];
}

// ---------------- CSR aggregation (fused softmax-denominator + elu) ----------------
// one wave per destination row; out[r,:] = elu( sum_e e*h[c_e,:] / (sum_e e + 1e-16) )
__global__ void agg64_kernel(const int* __restrict__ rowptr, const int* __restrict__ ecol,
                             const float* __restrict__ fs, const float* __restrict__ fd,
                             const float* __restrict__ h, float* __restrict__ out, int N) {
    int wv = (blockIdx.x * blockDim.x + threadIdx.x) >> 6;
    int lane = threadIdx.x & 63;
    if (wv >= N) return;
    int s = rowptr[wv], en = rowptr[wv + 1];
    float fsr = fs[wv];
    float acc = 0.f, den = 0.f;
    for (int j = s; j < en; ++j) {
        int c = ecol[j];
        float f = fsr + fd[c];
        float lr = f >= 0.f ? f : 0.2f * f;
        float e = expf(-lr);
        acc += e * h[(size_t)c * 64 + lane];
        den += e;
    }
    float v = acc / (den + 1e-16f);
    out[(size_t)wv * 64 + lane] = v > 0.f ? v : expm1f(v);
}

__global__ void agg128_kernel(const int* __restrict__ rowptr, const int* __restrict__ ecol,
                              const float* __restrict__ fs, const float* __restrict__ fd,
                              const float* __restrict__ h, float* __restrict__ out, int N) {
    int wv = (blockIdx.x * blockDim.x + threadIdx.x) >> 6;
    int lane = threadIdx.x & 63;
    if (wv >= N) return;
    int s = rowptr[wv], en = rowptr[wv + 1];
    float fsr = fs[wv];
    float acc0 = 0.f, acc1 = 0.f, den = 0.f;
    for (int j = s; j < en; ++j) {
        int c = ecol[j];
        float f = fsr + fd[c];
        float lr = f >= 0.f ? f : 0.2f * f;
        float e = expf(-lr);
        const float* hp = h + (size_t)c * 128;
        acc0 += e * hp[lane];
        acc1 += e * hp[lane + 64];
        den += e;
    }
    float inv = 1.0f / (den + 1e-16f);
    float v0 = acc0 * inv, v1 = acc1 * inv;
    out[(size_t)wv * 128 + lane] = v0 > 0.f ? v0 : expm1f(v0);
    out[(size_t)wv * 128 + lane + 64] = v1 > 0.f ? v1 : expm1f(v1);
}

// ---------------- output ----------------
__global__ void final_kernel(const float* __restrict__ twX, const float* __restrict__ tuX,
                             const int* __restrict__ twi, const int* __restrict__ tui,
                             const float* __restrict__ attsum,
                             const float* __restrict__ outW, const float* __restrict__ outb,
                             float* __restrict__ out, int B, float invNtw, float invNuv) {
    int wave = (blockIdx.x * blockDim.x + threadIdx.x) >> 6;
    int lane = threadIdx.x & 63;
    if (wave >= B) return;
    float z0 = attsum[0] * invNtw, z1 = attsum[1] * invNuv;
    float m = fmaxf(z0, z1);
    float e0 = expf(z0 - m), e1 = expf(z1 - m);
    float a0 = e0 / (e0 + e1), a1 = e1 / (e0 + e1);
    int ti = twi[wave], ui = tui[wave];
    float l0 = 0.f, l1 = 0.f;
#pragma unroll
    for (int p = 0; p < 2; ++p) {
        int j = lane + 64 * p;
        float feat = a0 * twX[(size_t)ti * 128 + j] + a1 * tuX[(size_t)ui * 128 + j];
        l0 += feat * outW[j];
        l1 += feat * outW[128 + j];
    }
    l0 = waveReduce(l0);
    l1 = waveReduce(l1);
    if (lane == 0) {
        l0 += outb[0];
        l1 += outb[1];
        float mm = fmaxf(l0, l1);
        float lse = mm + logf(expf(l0 - mm) + expf(l1 - mm));
        out[wave * 2 + 0] = l0 - lse;
        out[wave * 2 + 1] = l1 - lse;
    }
}

extern "C" void kernel_launch(void* const* d_in, const int* in_sizes, int n_in,
                              void* d_out, int out_size, void* d_ws, size_t ws_size,
                              hipStream_t stream) {
    const int* features_index = (const int*)d_in[0];
    const int* tw_edges = (const int*)d_in[1];
    const int* ut_edges = (const int*)d_in[2];
    const int* tw_gidx = (const int*)d_in[3];
    const int* ut_gidx = (const int*)d_in[4];
    const float* word_emb = (const float*)d_in[5];
    const float* user_emb = (const float*)d_in[6];
    const float* tw_W1 = (const float*)d_in[7];
    const float* tw_a1 = (const float*)d_in[8];
    const float* tw_W2 = (const float*)d_in[9];
    const float* tw_a2 = (const float*)d_in[10];
    const float* tu_W1 = (const float*)d_in[11];
    const float* tu_a1 = (const float*)d_in[12];
    const float* tu_W2 = (const float*)d_in[13];
    const float* tu_a2 = (const float*)d_in[14];
    const float* weight_W = (const float*)d_in[15];
    const float* weight_proj = (const float*)d_in[16];
    const float* out_W = (const float*)d_in[17];
    const float* out_b = (const float*)d_in[18];

    const int E = in_sizes[1] / 2;              // 800000
    const int NTW = in_sizes[0] / 16;           // 50000
    const int UV = in_sizes[6] / 300;           // 50000
    const int B = in_sizes[3];                  // 4096
    const int Nmax = NTW > UV ? NTW : UV;

    char* ws = (char*)d_ws;
    size_t off = 0;
    auto carve = [&](size_t bytes) -> void* {
        void* p = ws + off;
        off += (bytes + 255) & ~(size_t)255;
        return p;
    };
    bf16* twtX = (bf16*)carve((size_t)NTW * 300 * sizeof(bf16));
    float* bufH = (float*)carve((size_t)Nmax * 128 * sizeof(float));
    float* num1 = (float*)carve((size_t)Nmax * 64 * sizeof(float));
    float* twXf = (float*)carve((size_t)NTW * 128 * sizeof(float));
    float* tuXf = (float*)carve((size_t)UV * 128 * sizeof(float));
    float* f_s = (float*)carve((size_t)Nmax * sizeof(float));
    float* f_d = (float*)carve((size_t)Nmax * sizeof(float));
    float* attsum = (float*)carve(256);
    int* deg = (int*)carve((size_t)Nmax * sizeof(int));
    int* rowptr = (int*)carve((size_t)(Nmax + 1) * sizeof(int));
    int* cursor = (int*)carve((size_t)Nmax * sizeof(int));
    int* ecol = (int*)carve((size_t)E * sizeof(int));
    (void)ws_size; (void)n_in; (void)out_size;

    gather_mean_kernel<<<(NTW + 3) / 4, 256, 0, stream>>>(features_index, (const float4*)word_emb,
                                                          twtX, NTW);

    auto run_branch = [&](auto Xb, const int* edges, const float* W1, const float* a1,
                          const float* W2, const float* a2, float* Xfinal, int N) {
        const int* row = edges;
        const int* col = edges + E;
        int gT = (N + 15) / 16;
        int gE = (E + 255) / 256;
        int gW = (N + 3) / 4;   // one wave per row
        // CSR build (shared by both layers of this branch)
        zero_int_kernel<<<(N + 255) / 256, 256, 0, stream>>>(deg, N);
        count_kernel<<<gE, 256, 0, stream>>>(row, deg, E);
        scan_kernel<<<1, 1024, 0, stream>>>(deg, rowptr, cursor, N);
        scatter_kernel<<<gE, 256, 0, stream>>>(row, col, cursor, ecol, E);
        // layer 1 (d=64)
        gemm_l1<<<gT, 256, 0, stream>>>(Xb, W1, a1, bufH, f_s, f_d, N);
        agg64_kernel<<<gW, 256, 0, stream>>>(rowptr, ecol, f_s, f_d, bufH, num1, N);
        // layer 2 (d=128)
        gemm_l2<<<gT, 256, 0, stream>>>(num1, W2, a2, bufH, f_s, f_d, N);
        agg128_kernel<<<gW, 256, 0, stream>>>(rowptr, ecol, f_s, f_d, bufH, Xfinal, N);
    };

    run_branch((const bf16*)twtX, tw_edges, tw_W1, tw_a1, tw_W2, tw_a2, twXf, NTW);
    run_branch((const float*)user_emb, ut_edges, tu_W1, tu_a1, tu_W2, tu_a2, tuXf, UV);

    hipMemsetAsync(attsum, 0, 2 * sizeof(float), stream);
    att_tiled<<<(NTW + 15) / 16, 256, 0, stream>>>(twXf, weight_W, weight_proj, attsum + 0, NTW);
    att_tiled<<<(UV + 15) / 16, 256, 0, stream>>>(tuXf, weight_W, weight_proj, attsum + 1, UV);

    final_kernel<<<(B + 3) / 4, 256, 0, stream>>>(twXf, tuXf, tw_gidx, ut_gidx, attsum,
                                                  out_W, out_b, (float*)d_out, B,
                                                  1.0f / (float)NTW, 1.0f / (float)UV);
}

// Round 9
// 1180.915 us; speedup vs baseline: 3.0695x; 1.1982x over previous
//
#include <hip/hip_runtime.h>
#include <hip/hip_bf16.h>

typedef __hip_bfloat16 bf16;

__device__ __forceinline__ float waveReduce(float v) {
#pragma unroll
    for (int o = 32; o > 0; o >>= 1) v += __shfl_xor(v, o, 64);
    return v;
}

// ---------------- P = word_emb @ W1  (M x 300 @ 300 x 64), tiled, no epilogue ----------------
#define KC1 100
__global__ __launch_bounds__(256) void proj1_kernel(const float* __restrict__ X,
                                                    const float* __restrict__ W,
                                                    float* __restrict__ P, int M) {
    __shared__ float Ws[KC1 * 64];
    __shared__ float Xs[16 * KC1];
    int t = threadIdx.x;
    int c = t & 63;
    int rg = t >> 6;
    int row0 = blockIdx.x * 16;
    float acc[4] = {0.f, 0.f, 0.f, 0.f};
    for (int k0 = 0; k0 < 300; k0 += KC1) {
        for (int e = t; e < KC1 * 64; e += 256)
            Ws[e] = W[(size_t)(k0 + (e >> 6)) * 64 + (e & 63)];
        for (int e = t; e < 16 * KC1; e += 256) {
            int r = e / KC1, kk = e - r * KC1;
            int gr = row0 + r;
            Xs[e] = (gr < M) ? X[(size_t)gr * 300 + k0 + kk] : 0.f;
        }
        __syncthreads();
        for (int k = 0; k < KC1; ++k) {
            float wv = Ws[k * 64 + c];
#pragma unroll
            for (int i = 0; i < 4; ++i)
                acc[i] += Xs[(rg * 4 + i) * KC1 + k] * wv;
        }
        __syncthreads();
    }
#pragma unroll
    for (int i = 0; i < 4; ++i) {
        int gr = row0 + rg * 4 + i;
        if (gr < M) P[(size_t)gr * 64 + c] = acc[i];
    }
}

// h[i,:] = mean_16 P[idx[i,j],:]; fused fs=h.a[:64], fd=h.a[64:128]
__global__ void gather_h64(const int* __restrict__ idx, const float* __restrict__ P,
                           const float* __restrict__ a,
                           float* __restrict__ H, float* __restrict__ fs, float* __restrict__ fd,
                           int N) {
    int wv = (blockIdx.x * blockDim.x + threadIdx.x) >> 6;
    int lane = threadIdx.x & 63;
    if (wv >= N) return;
    const int* ip = idx + wv * 16;
    int inds[16];
#pragma unroll
    for (int j = 0; j < 16; ++j) inds[j] = ip[j];
    float acc = 0.f;
#pragma unroll
    for (int j = 0; j < 16; ++j) acc += P[(size_t)inds[j] * 64 + lane];
    acc *= 0.0625f;
    H[(size_t)wv * 64 + lane] = acc;
    float p = waveReduce(acc * a[lane]);
    float q = waveReduce(acc * a[64 + lane]);
    if (lane == 0) { fs[wv] = p; fd[wv] = q; }
}

// ---------------- layer-1 GEMM with fused f epilogue (user branch) ----------------
__global__ __launch_bounds__(256) void gemm_l1(const float* __restrict__ X,
                                               const float* __restrict__ W,
                                               const float* __restrict__ a,
                                               float* __restrict__ C,
                                               float* __restrict__ fs, float* __restrict__ fd,
                                               int M) {
    __shared__ float Ws[KC1 * 64];
    __shared__ float Xs[16 * KC1];
    int t = threadIdx.x;
    int c = t & 63;
    int rg = t >> 6;
    int row0 = blockIdx.x * 16;
    float acc[4] = {0.f, 0.f, 0.f, 0.f};
    for (int k0 = 0; k0 < 300; k0 += KC1) {
        for (int e = t; e < KC1 * 64; e += 256)
            Ws[e] = W[(size_t)(k0 + (e >> 6)) * 64 + (e & 63)];
        for (int e = t; e < 16 * KC1; e += 256) {
            int r = e / KC1, kk = e - r * KC1;
            int gr = row0 + r;
            Xs[e] = (gr < M) ? X[(size_t)gr * 300 + k0 + kk] : 0.f;
        }
        __syncthreads();
        for (int k = 0; k < KC1; ++k) {
            float wv = Ws[k * 64 + c];
#pragma unroll
            for (int i = 0; i < 4; ++i)
                acc[i] += Xs[(rg * 4 + i) * KC1 + k] * wv;
        }
        __syncthreads();
    }
#pragma unroll
    for (int i = 0; i < 4; ++i) {
        int gr = row0 + rg * 4 + i;
        if (gr < M) C[(size_t)gr * 64 + c] = acc[i];
    }
    float a0 = a[c], a1 = a[64 + c];
#pragma unroll
    for (int i = 0; i < 4; ++i) {
        float p = waveReduce(acc[i] * a0);
        float q = waveReduce(acc[i] * a1);
        int gr = row0 + rg * 4 + i;
        if (c == 0 && gr < M) { fs[gr] = p; fd[gr] = q; }
    }
}

// ---------------- layer-2 GEMM (unchanged) ----------------
__global__ __launch_bounds__(256) void gemm_l2(const float* __restrict__ H,
                                               const float* __restrict__ W,
                                               const float* __restrict__ a,
                                               float* __restrict__ C,
                                               float* __restrict__ fs, float* __restrict__ fd,
                                               int M) {
    __shared__ float Ws[64 * 128];
    __shared__ float Xs[16 * 64];
    __shared__ float fpart[2][16][2];
    int t = threadIdx.x;
    int c = t & 127;
    int rg = t >> 7;
    int half = (t >> 6) & 1;
    int row0 = blockIdx.x * 16;
    for (int e = t; e < 64 * 128; e += 256) Ws[e] = W[e];
    for (int e = t; e < 16 * 64; e += 256) {
        int gr = row0 + (e >> 6);
        Xs[e] = (gr < M) ? H[(size_t)gr * 64 + (e & 63)] : 0.f;
    }
    __syncthreads();
    float acc[8] = {0.f, 0.f, 0.f, 0.f, 0.f, 0.f, 0.f, 0.f};
    for (int k = 0; k < 64; ++k) {
        float wv = Ws[k * 128 + c];
#pragma unroll
        for (int i = 0; i < 8; ++i)
            acc[i] += Xs[(rg * 8 + i) * 64 + k] * wv;
    }
    float a0 = a[c], a1 = a[128 + c];
#pragma unroll
    for (int i = 0; i < 8; ++i) {
        int gr = row0 + rg * 8 + i;
        if (gr < M) C[(size_t)gr * 128 + c] = acc[i];
        float p = waveReduce(acc[i] * a0);
        float q = waveReduce(acc[i] * a1);
        if ((t & 63) == 0) { fpart[half][rg * 8 + i][0] = p; fpart[half][rg * 8 + i][1] = q; }
    }
    __syncthreads();
    if (t < 16) {
        int gr = row0 + t;
        if (gr < M) {
            fs[gr] = fpart[0][t][0] + fpart[1][t][0];
            fd[gr] = fpart[0][t][1] + fpart[1][t][1];
        }
    }
}

#define KCA 64
__global__ __launch_bounds__(256) void att_tiled(const float* __restrict__ X,
                                                 const float* __restrict__ W,
                                                 const float* __restrict__ proj,
                                                 float* __restrict__ attsum, int M) {
    __shared__ float Ws[KCA * 128];
    __shared__ float Xs[16 * KCA];
    __shared__ float bs[4];
    int t = threadIdx.x;
    int c = t & 127;
    int rg = t >> 7;
    int row0 = blockIdx.x * 16;
    float acc[8] = {0.f, 0.f, 0.f, 0.f, 0.f, 0.f, 0.f, 0.f};
    for (int k0 = 0; k0 < 128; k0 += KCA) {
        for (int e = t; e < KCA * 128; e += 256)
            Ws[e] = W[(size_t)(k0 + (e >> 7)) * 128 + (e & 127)];
        for (int e = t; e < 16 * KCA; e += 256) {
            int gr = row0 + (e / KCA);
            Xs[e] = (gr < M) ? X[(size_t)gr * 128 + k0 + (e % KCA)] : 0.f;
        }
        __syncthreads();
        for (int k = 0; k < KCA; ++k) {
            float wv = Ws[k * 128 + c];
#pragma unroll
            for (int i = 0; i < 8; ++i)
                acc[i] += Xs[(rg * 8 + i) * KCA + k] * wv;
        }
        __syncthreads();
    }
    float pj = proj[c];
    float s = 0.f;
#pragma unroll
    for (int i = 0; i < 8; ++i) {
        int gr = row0 + rg * 8 + i;
        if (gr < M) s += tanhf(acc[i]) * pj;
    }
    s = waveReduce(s);
    if ((t & 63) == 0) bs[t >> 6] = s;
    __syncthreads();
    if (t == 0) atomicAdd(attsum, bs[0] + bs[1] + bs[2] + bs[3]);
}

// ---------------- CSR build ----------------
__global__ void zero_int_kernel(int* p, int n) {
    int i = blockIdx.x * blockDim.x + threadIdx.x;
    if (i < n) p[i] = 0;
}

__global__ void count_kernel(const int* __restrict__ row, int* __restrict__ deg, int E) {
    int i = blockIdx.x * blockDim.x + threadIdx.x;
    if (i < E) atomicAdd(&deg[row[i]], 1);
}

__global__ __launch_bounds__(1024) void scan_kernel(const int* __restrict__ deg,
                                                    int* __restrict__ rowptr,
                                                    int* __restrict__ cursor, int N) {
    __shared__ int part[1024];
    int t = threadIdx.x;
    int chunk = (N + 1023) >> 10;
    int s = t * chunk;
    int e = s + chunk; if (e > N) e = N;
    int sum = 0;
    for (int i = s; i < e; ++i) sum += deg[i];
    part[t] = sum;
    __syncthreads();
    for (int off = 1; off < 1024; off <<= 1) {
        int v = (t >= off) ? part[t - off] : 0;
        __syncthreads();
        part[t] += v;
        __syncthreads();
    }
    int run = (t == 0) ? 0 : part[t - 1];
    for (int i = s; i < e; ++i) {
        rowptr[i] = run;
        cursor[i] = run;
        run += deg[i];
    }
    if (t == 1023) rowptr[N] = part[1023];
}

__global__ void scatter_kernel(const int* __restrict__ row, const int* __restrict__ col,
                               int* __restrict__ cursor, int* __restrict__ ecol, int E) {
    int i = blockIdx.x * blockDim.x + threadIdx.x;
    if (i >= E) return;
    int p = atomicAdd(&cursor[row[i]], 1);
    ecol[p] = col[i];
}

// ---------------- CSR aggregation ----------------
__global__ void agg64_kernel(const int* __restrict__ rowptr, const int* __restrict__ ecol,
                             const float* __restrict__ fs, const float* __restrict__ fd,
                             const float* __restrict__ h, float* __restrict__ out, int N) {
    int wv = (blockIdx.x * blockDim.x + threadIdx.x) >> 6;
    int lane = threadIdx.x & 63;
    if (wv >= N) return;
    int s = rowptr[wv], en = rowptr[wv + 1];
    float fsr = fs[wv];
    float acc0 = 0.f, acc1 = 0.f, den = 0.f;
    int j = s;
    for (; j + 1 < en; j += 2) {
        int c0 = ecol[j], c1 = ecol[j + 1];
        float f0 = fsr + fd[c0], f1 = fsr + fd[c1];
        float e0 = expf(-(f0 >= 0.f ? f0 : 0.2f * f0));
        float e1 = expf(-(f1 >= 0.f ? f1 : 0.2f * f1));
        acc0 += e0 * h[(size_t)c0 * 64 + lane];
        acc1 += e1 * h[(size_t)c1 * 64 + lane];
        den += e0 + e1;
    }
    if (j < en) {
        int c = ecol[j];
        float f = fsr + fd[c];
        float e = expf(-(f >= 0.f ? f : 0.2f * f));
        acc0 += e * h[(size_t)c * 64 + lane];
        den += e;
    }
    float v = (acc0 + acc1) / (den + 1e-16f);
    out[(size_t)wv * 64 + lane] = v > 0.f ? v : expm1f(v);
}

__global__ void agg128_kernel(const int* __restrict__ rowptr, const int* __restrict__ ecol,
                              const float* __restrict__ fs, const float* __restrict__ fd,
                              const float2* __restrict__ h, float2* __restrict__ out, int N) {
    int wv = (blockIdx.x * blockDim.x + threadIdx.x) >> 6;
    int lane = threadIdx.x & 63;
    if (wv >= N) return;
    int s = rowptr[wv], en = rowptr[wv + 1];
    float fsr = fs[wv];
    float ax = 0.f, ay = 0.f, bx = 0.f, by = 0.f, den = 0.f;
    int j = s;
    for (; j + 1 < en; j += 2) {
        int c0 = ecol[j], c1 = ecol[j + 1];
        float f0 = fsr + fd[c0], f1 = fsr + fd[c1];
        float e0 = expf(-(f0 >= 0.f ? f0 : 0.2f * f0));
        float e1 = expf(-(f1 >= 0.f ? f1 : 0.2f * f1));
        float2 v0 = h[(size_t)c0 * 64 + lane];
        float2 v1 = h[(size_t)c1 * 64 + lane];
        ax += e0 * v0.x; ay += e0 * v0.y;
        bx += e1 * v1.x; by += e1 * v1.y;
        den += e0 + e1;
    }
    if (j < en) {
        int c = ecol[j];
        float f = fsr + fd[c];
        float e = expf(-(f >= 0.f ? f : 0.2f * f));
        float2 v = h[(size_t)c * 64 + lane];
        ax += e * v.x; ay += e * v.y;
        den += e;
    }
    float inv = 1.0f / (den + 1e-16f);
    float vx = (ax + bx) * inv, vy = (ay + by) * inv;
    float2 o;
    o.x = vx > 0.f ? vx : expm1f(vx);
    o.y = vy > 0.f ? vy : expm1f(vy);
    out[(size_t)wv * 64 + lane] = o;
}

// ---------------- output ----------------
__global__ void final_kernel(const float* __restrict__ twX, const float* __restrict__ tuX,
                             const int* __restrict__ twi, const int* __restrict__ tui,
                             const float* __restrict__ attsum,
                             const float* __restrict__ outW, const float* __restrict__ outb,
                             float* __restrict__ out, int B, float invNtw, float invNuv) {
    int wave = (blockIdx.x * blockDim.x + threadIdx.x) >> 6;
    int lane = threadIdx.x & 63;
    if (wave >= B) return;
    float z0 = attsum[0] * invNtw, z1 = attsum[1] * invNuv;
    float m = fmaxf(z0, z1);
    float e0 = expf(z0 - m), e1 = expf(z1 - m);
    float a0 = e0 / (e0 + e1), a1 = e1 / (e0 + e1);
    int ti = twi[wave], ui = tui[wave];
    float l0 = 0.f, l1 = 0.f;
#pragma unroll
    for (int p = 0; p < 2; ++p) {
        int j = lane + 64 * p;
        float feat = a0 * twX[(size_t)ti * 128 + j] + a1 * tuX[(size_t)ui * 128 + j];
        l0 += feat * outW[j];
        l1 += feat * outW[128 + j];
    }
    l0 = waveReduce(l0);
    l1 = waveReduce(l1);
    if (lane == 0) {
        l0 += outb[0];
        l1 += outb[1];
        float mm = fmaxf(l0, l1);
        float lse = mm + logf(expf(l0 - mm) + expf(l1 - mm));
        out[wave * 2 + 0] = l0 - lse;
        out[wave * 2 + 1] = l1 - lse;
    }
}

extern "C" void kernel_launch(void* const* d_in, const int* in_sizes, int n_in,
                              void* d_out, int out_size, void* d_ws, size_t ws_size,
                              hipStream_t stream) {
    const int* features_index = (const int*)d_in[0];
    const int* tw_edges = (const int*)d_in[1];
    const int* ut_edges = (const int*)d_in[2];
    const int* tw_gidx = (const int*)d_in[3];
    const int* ut_gidx = (const int*)d_in[4];
    const float* word_emb = (const float*)d_in[5];
    const float* user_emb = (const float*)d_in[6];
    const float* tw_W1 = (const float*)d_in[7];
    const float* tw_a1 = (const float*)d_in[8];
    const float* tw_W2 = (const float*)d_in[9];
    const float* tw_a2 = (const float*)d_in[10];
    const float* tu_W1 = (const float*)d_in[11];
    const float* tu_a1 = (const float*)d_in[12];
    const float* tu_W2 = (const float*)d_in[13];
    const float* tu_a2 = (const float*)d_in[14];
    const float* weight_W = (const float*)d_in[15];
    const float* weight_proj = (const float*)d_in[16];
    const float* out_W = (const float*)d_in[17];
    const float* out_b = (const float*)d_in[18];

    const int E = in_sizes[1] / 2;              // 800000
    const int NTW = in_sizes[0] / 16;           // 50000
    const int VOCAB = in_sizes[5] / 300;        // 50000
    const int UV = in_sizes[6] / 300;           // 50000
    const int B = in_sizes[3];                  // 4096
    const int Nmax = NTW > UV ? NTW : UV;
    const int Pmax = VOCAB > Nmax ? VOCAB : Nmax;

    char* ws = (char*)d_ws;
    size_t off = 0;
    auto carve = [&](size_t bytes) -> void* {
        void* p = ws + off;
        off += (bytes + 255) & ~(size_t)255;
        return p;
    };
    float* Pbuf = (float*)carve((size_t)Pmax * 64 * sizeof(float));   // word_emb@W1 projection
    float* bufH = (float*)carve((size_t)Nmax * 128 * sizeof(float));
    float* num1 = (float*)carve((size_t)Nmax * 64 * sizeof(float));
    float* twXf = (float*)carve((size_t)NTW * 128 * sizeof(float));
    float* tuXf = (float*)carve((size_t)UV * 128 * sizeof(float));
    float* f_s = (float*)carve((size_t)Nmax * sizeof(float));
    float* f_d = (float*)carve((size_t)Nmax * sizeof(float));
    float* attsum = (float*)carve(256);
    int* deg = (int*)carve((size_t)Nmax * sizeof(int));
    int* rowptr = (int*)carve((size_t)(Nmax + 1) * sizeof(int));
    int* cursor = (int*)carve((size_t)Nmax * sizeof(int));
    int* ecol = (int*)carve((size_t)E * sizeof(int));
    (void)ws_size; (void)n_in; (void)out_size;

    int gE = (E + 255) / 256;

    // ================= tweet branch =================
    {
        const int* row = tw_edges;
        const int* col = tw_edges + E;
        int N = NTW;
        // CSR
        zero_int_kernel<<<(N + 255) / 256, 256, 0, stream>>>(deg, N);
        count_kernel<<<gE, 256, 0, stream>>>(row, deg, E);
        scan_kernel<<<1, 1024, 0, stream>>>(deg, rowptr, cursor, N);
        scatter_kernel<<<gE, 256, 0, stream>>>(row, col, cursor, ecol, E);
        // layer 1: project vocab then gather  (mean ∘ matmul reorder)
        proj1_kernel<<<(VOCAB + 15) / 16, 256, 0, stream>>>(word_emb, tw_W1, Pbuf, VOCAB);
        gather_h64<<<(N + 3) / 4, 256, 0, stream>>>(features_index, Pbuf, tw_a1,
                                                    bufH, f_s, f_d, N);
        agg64_kernel<<<(N + 3) / 4, 256, 0, stream>>>(rowptr, ecol, f_s, f_d, bufH, num1, N);
        // layer 2
        gemm_l2<<<(N + 15) / 16, 256, 0, stream>>>(num1, tw_W2, tw_a2, bufH, f_s, f_d, N);
        agg128_kernel<<<(N + 3) / 4, 256, 0, stream>>>(rowptr, ecol, f_s, f_d,
                                                       (const float2*)bufH, (float2*)twXf, N);
    }
    // ================= user branch =================
    {
        const int* row = ut_edges;
        const int* col = ut_edges + E;
        int N = UV;
        zero_int_kernel<<<(N + 255) / 256, 256, 0, stream>>>(deg, N);
        count_kernel<<<gE, 256, 0, stream>>>(row, deg, E);
        scan_kernel<<<1, 1024, 0, stream>>>(deg, rowptr, cursor, N);
        scatter_kernel<<<gE, 256, 0, stream>>>(row, col, cursor, ecol, E);
        gemm_l1<<<(N + 15) / 16, 256, 0, stream>>>(user_emb, tu_W1, tu_a1, bufH, f_s, f_d, N);
        agg64_kernel<<<(N + 3) / 4, 256, 0, stream>>>(rowptr, ecol, f_s, f_d, bufH, num1, N);
        gemm_l2<<<(N + 15) / 16, 256, 0, stream>>>(num1, tu_W2, tu_a2, bufH, f_s, f_d, N);
        agg128_kernel<<<(N + 3) / 4, 256, 0, stream>>>(rowptr, ecol, f_s, f_d,
                                                       (const float2*)bufH, (float2*)tuXf, N);
    }

    hipMemsetAsync(attsum, 0, 2 * sizeof(float), stream);
    att_tiled<<<(NTW + 15) / 16, 256, 0, stream>>>(twXf, weight_W, weight_proj, attsum + 0, NTW);
    att_tiled<<<(UV + 15) / 16, 256, 0, stream>>>(tuXf, weight_W, weight_proj, attsum + 1, UV);

    final_kernel<<<(B + 3) / 4, 256, 0, stream>>>(twXf, tuXf, tw_gidx, ut_gidx, attsum,
                                                  out_W, out_b, (float*)d_out, B,
                                                  1.0f / (float)NTW, 1.0f / (float)UV);
}

// Round 10
// 993.407 us; speedup vs baseline: 3.6489x; 1.1888x over previous
//
#include <hip/hip_runtime.h>
#include <hip/hip_bf16.h>

typedef __hip_bfloat16 bf16;
typedef __attribute__((ext_vector_type(8))) short bf8v;   // 8 bf16 = 4 VGPRs
typedef __attribute__((ext_vector_type(4))) float f4v;    // MFMA accumulator

__device__ __forceinline__ float waveReduce(float v) {
#pragma unroll
    for (int o = 32; o > 0; o >>= 1) v += __shfl_xor(v, o, 64);
    return v;
}

__device__ __forceinline__ short f2bf(float x) {
    __hip_bfloat16 h = __float2bfloat16(x);
    return *reinterpret_cast<short*>(&h);
}

// W[K,N] (fp32) -> Wt[N,KPAD] (bf16, zero-padded past K)
__global__ void wtrans_kernel(const float* __restrict__ W, short* __restrict__ Wt,
                              int K, int N, int KPAD) {
    int i = blockIdx.x * blockDim.x + threadIdx.x;
    if (i >= N * KPAD) return;
    int n = i / KPAD, k = i - n * KPAD;
    Wt[i] = f2bf(k < K ? W[(size_t)k * N + n] : 0.f);
}

// ---------------- universal MFMA GEMM ----------------
// C[M,N] = A[M,K] @ W[K,N]  (A fp32 global, W pre-transposed bf16 [N,KPAD])
// STORE_C: write C (fp32). DO_F: fs=C.av[0:N], fd=C.av[N:2N]. DO_ATT: attsum += sum tanh(C).av
template <int K, int KPAD, int N, bool STORE_C, bool DO_F, bool DO_ATT>
__global__ __launch_bounds__(256) void mfma_gemm(const float* __restrict__ A,
                                                 const short* __restrict__ Wt,
                                                 const float* __restrict__ av,
                                                 float* __restrict__ C,
                                                 float* __restrict__ fs, float* __restrict__ fd,
                                                 float* __restrict__ attsum, int M) {
    constexpr int NT = N / 16;     // n-tiles per wave
    constexpr int NP = KPAD / 64;  // k-panels
    __shared__ short As[64 * 72];  // 64 rows x (64+8 pad)
    __shared__ short Ws[N * 72];
    __shared__ float red[4];
    int t = threadIdx.x;
    int lane = t & 63;
    int wid = t >> 6;
    int col = lane & 15;
    int quad = lane >> 4;
    int row0 = blockIdx.x * 64;

    f4v acc[NT];
#pragma unroll
    for (int i = 0; i < NT; ++i) { f4v z = {0.f, 0.f, 0.f, 0.f}; acc[i] = z; }

    for (int p = 0; p < NP; ++p) {
        int k0 = p * 64;
        // stage A panel (fp32 -> bf16), zero-pad rows >= M and k >= K
        for (int r = wid; r < 64; r += 4) {
            int gr = row0 + r;
            int kk = k0 + lane;
            float v = (gr < M && kk < K) ? A[(size_t)gr * K + kk] : 0.f;
            As[r * 72 + lane] = f2bf(v);
        }
        // stage Wt panel (already bf16, rows contiguous)
        for (int r = wid; r < N; r += 4)
            Ws[r * 72 + lane] = Wt[(size_t)r * KPAD + k0 + lane];
        __syncthreads();
#pragma unroll
        for (int c2 = 0; c2 < 2; ++c2) {
            int ko = c2 * 32 + quad * 8;
            bf8v af = *(const bf8v*)&As[(wid * 16 + col) * 72 + ko];
#pragma unroll
            for (int nt = 0; nt < NT; ++nt) {
                bf8v bf = *(const bf8v*)&Ws[(nt * 16 + col) * 72 + ko];
                acc[nt] = __builtin_amdgcn_mfma_f32_16x16x32_bf16(af, bf, acc[nt], 0, 0, 0);
            }
        }
        __syncthreads();
    }

    int mbase = row0 + wid * 16;
    if constexpr (STORE_C) {
#pragma unroll
        for (int nt = 0; nt < NT; ++nt)
#pragma unroll
            for (int r = 0; r < 4; ++r) {
                int gr = mbase + quad * 4 + r;
                if (gr < M) C[(size_t)gr * N + nt * 16 + col] = acc[nt][r];
            }
    }
    if constexpr (DO_F) {
        float a0[NT], a1[NT];
#pragma unroll
        for (int nt = 0; nt < NT; ++nt) {
            a0[nt] = av[nt * 16 + col];
            a1[nt] = av[N + nt * 16 + col];
        }
#pragma unroll
        for (int r = 0; r < 4; ++r) {
            float p0 = 0.f, p1 = 0.f;
#pragma unroll
            for (int nt = 0; nt < NT; ++nt) {
                p0 += acc[nt][r] * a0[nt];
                p1 += acc[nt][r] * a1[nt];
            }
#pragma unroll
            for (int o = 8; o > 0; o >>= 1) {
                p0 += __shfl_xor(p0, o, 64);
                p1 += __shfl_xor(p1, o, 64);
            }
            int gr = mbase + quad * 4 + r;
            if (col == 0 && gr < M) { fs[gr] = p0; fd[gr] = p1; }
        }
    }
    if constexpr (DO_ATT) {
        float s = 0.f;
#pragma unroll
        for (int nt = 0; nt < NT; ++nt) {
            float pj = av[nt * 16 + col];
#pragma unroll
            for (int r = 0; r < 4; ++r) s += tanhf(acc[nt][r]) * pj;  // tail rows: tanh(0)=0
        }
        s = waveReduce(s);
        if (lane == 0) red[wid] = s;
        __syncthreads();
        if (t == 0) atomicAdd(attsum, red[0] + red[1] + red[2] + red[3]);
    }
}

// h[i,:] = mean_16 P[idx[i,j],:]; fused fs=h.a[:64], fd=h.a[64:128]
__global__ void gather_h64(const int* __restrict__ idx, const float* __restrict__ P,
                           const float* __restrict__ a,
                           float* __restrict__ H, float* __restrict__ fs, float* __restrict__ fd,
                           int N) {
    int wv = (blockIdx.x * blockDim.x + threadIdx.x) >> 6;
    int lane = threadIdx.x & 63;
    if (wv >= N) return;
    const int* ip = idx + wv * 16;
    int inds[16];
#pragma unroll
    for (int j = 0; j < 16; ++j) inds[j] = ip[j];
    float acc = 0.f;
#pragma unroll
    for (int j = 0; j < 16; ++j) acc += P[(size_t)inds[j] * 64 + lane];
    acc *= 0.0625f;
    H[(size_t)wv * 64 + lane] = acc;
    float p = waveReduce(acc * a[lane]);
    float q = waveReduce(acc * a[64 + lane]);
    if (lane == 0) { fs[wv] = p; fd[wv] = q; }
}

// ---------------- CSR build ----------------
__global__ void zero_int_kernel(int* p, int n) {
    int i = blockIdx.x * blockDim.x + threadIdx.x;
    if (i < n) p[i] = 0;
}

__global__ void count_kernel(const int* __restrict__ row, int* __restrict__ deg, int E) {
    int i = blockIdx.x * blockDim.x + threadIdx.x;
    if (i < E) atomicAdd(&deg[row[i]], 1);
}

__global__ __launch_bounds__(1024) void scan_kernel(const int* __restrict__ deg,
                                                    int* __restrict__ rowptr,
                                                    int* __restrict__ cursor, int N) {
    __shared__ int part[1024];
    int t = threadIdx.x;
    int chunk = (N + 1023) >> 10;
    int s = t * chunk;
    int e = s + chunk; if (e > N) e = N;
    int sum = 0;
    for (int i = s; i < e; ++i) sum += deg[i];
    part[t] = sum;
    __syncthreads();
    for (int off = 1; off < 1024; off <<= 1) {
        int v = (t >= off) ? part[t - off] : 0;
        __syncthreads();
        part[t] += v;
        __syncthreads();
    }
    int run = (t == 0) ? 0 : part[t - 1];
    for (int i = s; i < e; ++i) {
        rowptr[i] = run;
        cursor[i] = run;
        run += deg[i];
    }
    if (t == 1023) rowptr[N] = part[1023];
}

__global__ void scatter_kernel(const int* __restrict__ row, const int* __restrict__ col,
                               int* __restrict__ cursor, int* __restrict__ ecol, int E) {
    int i = blockIdx.x * blockDim.x + threadIdx.x;
    if (i >= E) return;
    int p = atomicAdd(&cursor[row[i]], 1);
    ecol[p] = col[i];
}

// ---------------- CSR aggregation ----------------
__global__ void agg64_kernel(const int* __restrict__ rowptr, const int* __restrict__ ecol,
                             const float* __restrict__ fs, const float* __restrict__ fd,
                             const float* __restrict__ h, float* __restrict__ out, int N) {
    int wv = (blockIdx.x * blockDim.x + threadIdx.x) >> 6;
    int lane = threadIdx.x & 63;
    if (wv >= N) return;
    int s = rowptr[wv], en = rowptr[wv + 1];
    float fsr = fs[wv];
    float acc0 = 0.f, acc1 = 0.f, den = 0.f;
    int j = s;
    for (; j + 1 < en; j += 2) {
        int c0 = ecol[j], c1 = ecol[j + 1];
        float f0 = fsr + fd[c0], f1 = fsr + fd[c1];
        float e0 = expf(-(f0 >= 0.f ? f0 : 0.2f * f0));
        float e1 = expf(-(f1 >= 0.f ? f1 : 0.2f * f1));
        acc0 += e0 * h[(size_t)c0 * 64 + lane];
        acc1 += e1 * h[(size_t)c1 * 64 + lane];
        den += e0 + e1;
    }
    if (j < en) {
        int c = ecol[j];
        float f = fsr + fd[c];
        float e = expf(-(f >= 0.f ? f : 0.2f * f));
        acc0 += e * h[(size_t)c * 64 + lane];
        den += e;
    }
    float v = (acc0 + acc1) / (den + 1e-16f);
    out[(size_t)wv * 64 + lane] = v > 0.f ? v : expm1f(v);
}

__global__ void agg128_kernel(const int* __restrict__ rowptr, const int* __restrict__ ecol,
                              const float* __restrict__ fs, const float* __restrict__ fd,
                              const float2* __restrict__ h, float2* __restrict__ out, int N) {
    int wv = (blockIdx.x * blockDim.x + threadIdx.x) >> 6;
    int lane = threadIdx.x & 63;
    if (wv >= N) return;
    int s = rowptr[wv], en = rowptr[wv + 1];
    float fsr = fs[wv];
    float ax = 0.f, ay = 0.f, bx = 0.f, by = 0.f, den = 0.f;
    int j = s;
    for (; j + 1 < en; j += 2) {
        int c0 = ecol[j], c1 = ecol[j + 1];
        float f0 = fsr + fd[c0], f1 = fsr + fd[c1];
        float e0 = expf(-(f0 >= 0.f ? f0 : 0.2f * f0));
        float e1 = expf(-(f1 >= 0.f ? f1 : 0.2f * f1));
        float2 v0 = h[(size_t)c0 * 64 + lane];
        float2 v1 = h[(size_t)c1 * 64 + lane];
        ax += e0 * v0.x; ay += e0 * v0.y;
        bx += e1 * v1.x; by += e1 * v1.y;
        den += e0 + e1;
    }
    if (j < en) {
        int c = ecol[j];
        float f = fsr + fd[c];
        float e = expf(-(f >= 0.f ? f : 0.2f * f));
        float2 v = h[(size_t)c * 64 + lane];
        ax += e * v.x; ay += e * v.y;
        den += e;
    }
    float inv = 1.0f / (den + 1e-16f);
    float vx = (ax + bx) * inv, vy = (ay + by) * inv;
    float2 o;
    o.x = vx > 0.f ? vx : expm1f(vx);
    o.y = vy > 0.f ? vy : expm1f(vy);
    out[(size_t)wv * 64 + lane] = o;
}

// ---------------- output ----------------
__global__ void final_kernel(const float* __restrict__ twX, const float* __restrict__ tuX,
                             const int* __restrict__ twi, const int* __restrict__ tui,
                             const float* __restrict__ attsum,
                             const float* __restrict__ outW, const float* __restrict__ outb,
                             float* __restrict__ out, int B, float invNtw, float invNuv) {
    int wave = (blockIdx.x * blockDim.x + threadIdx.x) >> 6;
    int lane = threadIdx.x & 63;
    if (wave >= B) return;
    float z0 = attsum[0] * invNtw, z1 = attsum[1] * invNuv;
    float m = fmaxf(z0, z1);
    float e0 = expf(z0 - m), e1 = expf(z1 - m);
    float a0 = e0 / (e0 + e1), a1 = e1 / (e0 + e1);
    int ti = twi[wave], ui = tui[wave];
    float l0 = 0.f, l1 = 0.f;
#pragma unroll
    for (int p = 0; p < 2; ++p) {
        int j = lane + 64 * p;
        float feat = a0 * twX[(size_t)ti * 128 + j] + a1 * tuX[(size_t)ui * 128 + j];
        l0 += feat * outW[j];
        l1 += feat * outW[128 + j];
    }
    l0 = waveReduce(l0);
    l1 = waveReduce(l1);
    if (lane == 0) {
        l0 += outb[0];
        l1 += outb[1];
        float mm = fmaxf(l0, l1);
        float lse = mm + logf(expf(l0 - mm) + expf(l1 - mm));
        out[wave * 2 + 0] = l0 - lse;
        out[wave * 2 + 1] = l1 - lse;
    }
}

extern "C" void kernel_launch(void* const* d_in, const int* in_sizes, int n_in,
                              void* d_out, int out_size, void* d_ws, size_t ws_size,
                              hipStream_t stream) {
    const int* features_index = (const int*)d_in[0];
    const int* tw_edges = (const int*)d_in[1];
    const int* ut_edges = (const int*)d_in[2];
    const int* tw_gidx = (const int*)d_in[3];
    const int* ut_gidx = (const int*)d_in[4];
    const float* word_emb = (const float*)d_in[5];
    const float* user_emb = (const float*)d_in[6];
    const float* tw_W1 = (const float*)d_in[7];
    const float* tw_a1 = (const float*)d_in[8];
    const float* tw_W2 = (const float*)d_in[9];
    const float* tw_a2 = (const float*)d_in[10];
    const float* tu_W1 = (const float*)d_in[11];
    const float* tu_a1 = (const float*)d_in[12];
    const float* tu_W2 = (const float*)d_in[13];
    const float* tu_a2 = (const float*)d_in[14];
    const float* weight_W = (const float*)d_in[15];
    const float* weight_proj = (const float*)d_in[16];
    const float* out_W = (const float*)d_in[17];
    const float* out_b = (const float*)d_in[18];

    const int E = in_sizes[1] / 2;              // 800000
    const int NTW = in_sizes[0] / 16;           // 50000
    const int VOCAB = in_sizes[5] / 300;        // 50000
    const int UV = in_sizes[6] / 300;           // 50000
    const int B = in_sizes[3];                  // 4096
    const int Nmax = NTW > UV ? NTW : UV;
    const int Pmax = VOCAB > Nmax ? VOCAB : Nmax;

    char* ws = (char*)d_ws;
    size_t off = 0;
    auto carve = [&](size_t bytes) -> void* {
        void* p = ws + off;
        off += (bytes + 255) & ~(size_t)255;
        return p;
    };
    float* Pbuf = (float*)carve((size_t)Pmax * 64 * sizeof(float));
    float* bufH = (float*)carve((size_t)Nmax * 128 * sizeof(float));
    float* num1 = (float*)carve((size_t)Nmax * 64 * sizeof(float));
    float* twXf = (float*)carve((size_t)NTW * 128 * sizeof(float));
    float* tuXf = (float*)carve((size_t)UV * 128 * sizeof(float));
    float* f_s = (float*)carve((size_t)Nmax * sizeof(float));
    float* f_d = (float*)carve((size_t)Nmax * sizeof(float));
    float* attsum = (float*)carve(256);
    int* deg = (int*)carve((size_t)Nmax * sizeof(int));
    int* rowptr = (int*)carve((size_t)(Nmax + 1) * sizeof(int));
    int* cursor = (int*)carve((size_t)Nmax * sizeof(int));
    int* ecol = (int*)carve((size_t)E * sizeof(int));
    short* Wt1tw = (short*)carve((size_t)64 * 320 * sizeof(short));
    short* Wt1tu = (short*)carve((size_t)64 * 320 * sizeof(short));
    short* Wt2tw = (short*)carve((size_t)128 * 64 * sizeof(short));
    short* Wt2tu = (short*)carve((size_t)128 * 64 * sizeof(short));
    short* Wta   = (short*)carve((size_t)128 * 128 * sizeof(short));
    (void)ws_size; (void)n_in; (void)out_size;

    int gE = (E + 255) / 256;

    // weight transposes (tiny)
    wtrans_kernel<<<(64 * 320 + 255) / 256, 256, 0, stream>>>(tw_W1, Wt1tw, 300, 64, 320);
    wtrans_kernel<<<(64 * 320 + 255) / 256, 256, 0, stream>>>(tu_W1, Wt1tu, 300, 64, 320);
    wtrans_kernel<<<(128 * 64 + 255) / 256, 256, 0, stream>>>(tw_W2, Wt2tw, 64, 128, 64);
    wtrans_kernel<<<(128 * 64 + 255) / 256, 256, 0, stream>>>(tu_W2, Wt2tu, 64, 128, 64);
    wtrans_kernel<<<(128 * 128 + 255) / 256, 256, 0, stream>>>(weight_W, Wta, 128, 128, 128);

    // ================= tweet branch =================
    {
        const int* row = tw_edges;
        const int* col = tw_edges + E;
        int N = NTW;
        zero_int_kernel<<<(N + 255) / 256, 256, 0, stream>>>(deg, N);
        count_kernel<<<gE, 256, 0, stream>>>(row, deg, E);
        scan_kernel<<<1, 1024, 0, stream>>>(deg, rowptr, cursor, N);
        scatter_kernel<<<gE, 256, 0, stream>>>(row, col, cursor, ecol, E);
        // P = word_emb @ W1  (mean ∘ matmul reorder), then gather
        mfma_gemm<300, 320, 64, true, false, false><<<(VOCAB + 63) / 64, 256, 0, stream>>>(
            word_emb, Wt1tw, nullptr, Pbuf, nullptr, nullptr, nullptr, VOCAB);
        gather_h64<<<(N + 3) / 4, 256, 0, stream>>>(features_index, Pbuf, tw_a1,
                                                    bufH, f_s, f_d, N);
        agg64_kernel<<<(N + 3) / 4, 256, 0, stream>>>(rowptr, ecol, f_s, f_d, bufH, num1, N);
        mfma_gemm<64, 64, 128, true, true, false><<<(N + 63) / 64, 256, 0, stream>>>(
            num1, Wt2tw, tw_a2, bufH, f_s, f_d, nullptr, N);
        agg128_kernel<<<(N + 3) / 4, 256, 0, stream>>>(rowptr, ecol, f_s, f_d,
                                                       (const float2*)bufH, (float2*)twXf, N);
    }
    // ================= user branch =================
    {
        const int* row = ut_edges;
        const int* col = ut_edges + E;
        int N = UV;
        zero_int_kernel<<<(N + 255) / 256, 256, 0, stream>>>(deg, N);
        count_kernel<<<gE, 256, 0, stream>>>(row, deg, E);
        scan_kernel<<<1, 1024, 0, stream>>>(deg, rowptr, cursor, N);
        scatter_kernel<<<gE, 256, 0, stream>>>(row, col, cursor, ecol, E);
        mfma_gemm<300, 320, 64, true, true, false><<<(N + 63) / 64, 256, 0, stream>>>(
            user_emb, Wt1tu, tu_a1, bufH, f_s, f_d, nullptr, N);
        agg64_kernel<<<(N + 3) / 4, 256, 0, stream>>>(rowptr, ecol, f_s, f_d, bufH, num1, N);
        mfma_gemm<64, 64, 128, true, true, false><<<(N + 63) / 64, 256, 0, stream>>>(
            num1, Wt2tu, tu_a2, bufH, f_s, f_d, nullptr, N);
        agg128_kernel<<<(N + 3) / 4, 256, 0, stream>>>(rowptr, ecol, f_s, f_d,
                                                       (const float2*)bufH, (float2*)tuXf, N);
    }

    hipMemsetAsync(attsum, 0, 2 * sizeof(float), stream);
    mfma_gemm<128, 128, 128, false, false, true><<<(NTW + 63) / 64, 256, 0, stream>>>(
        twXf, Wta, weight_proj, nullptr, nullptr, nullptr, attsum + 0, NTW);
    mfma_gemm<128, 128, 128, false, false, true><<<(UV + 63) / 64, 256, 0, stream>>>(
        tuXf, Wta, weight_proj, nullptr, nullptr, nullptr, attsum + 1, UV);

    final_kernel<<<(B + 3) / 4, 256, 0, stream>>>(twXf, tuXf, tw_gidx, ut_gidx, attsum,
                                                  out_W, out_b, (float*)d_out, B,
                                                  1.0f / (float)NTW, 1.0f / (float)UV);
}

// Round 11
// 802.577 us; speedup vs baseline: 4.5165x; 1.2378x over previous
//
#include <hip/hip_runtime.h>
#include <hip/hip_bf16.h>

typedef __hip_bfloat16 bf16;
typedef __attribute__((ext_vector_type(8))) short bf8v;   // 8 bf16 = 4 VGPRs
typedef __attribute__((ext_vector_type(4))) float f4v;    // MFMA accumulator

__device__ __forceinline__ float waveReduce(float v) {
#pragma unroll
    for (int o = 32; o > 0; o >>= 1) v += __shfl_xor(v, o, 64);
    return v;
}

__device__ __forceinline__ short f2bf(float x) {
    __hip_bfloat16 h = __float2bfloat16(x);
    return *reinterpret_cast<short*>(&h);
}

// W[K,N] (fp32) -> Wt[N,KPAD] (bf16, zero-padded past K)
__global__ void wtrans_kernel(const float* __restrict__ W, short* __restrict__ Wt,
                              int K, int N, int KPAD) {
    int i = blockIdx.x * blockDim.x + threadIdx.x;
    if (i >= N * KPAD) return;
    int n = i / KPAD, k = i - n * KPAD;
    Wt[i] = f2bf(k < K ? W[(size_t)k * N + n] : 0.f);
}

// ---------------- universal MFMA GEMM (verified R10) ----------------
template <int K, int KPAD, int N, bool STORE_C, bool DO_F, bool DO_ATT>
__global__ __launch_bounds__(256) void mfma_gemm(const float* __restrict__ A,
                                                 const short* __restrict__ Wt,
                                                 const float* __restrict__ av,
                                                 float* __restrict__ C,
                                                 float* __restrict__ fs, float* __restrict__ fd,
                                                 float* __restrict__ attsum, int M) {
    constexpr int NT = N / 16;
    constexpr int NP = KPAD / 64;
    __shared__ short As[64 * 72];
    __shared__ short Ws[N * 72];
    __shared__ float red[4];
    int t = threadIdx.x;
    int lane = t & 63;
    int wid = t >> 6;
    int col = lane & 15;
    int quad = lane >> 4;
    int row0 = blockIdx.x * 64;

    f4v acc[NT];
#pragma unroll
    for (int i = 0; i < NT; ++i) { f4v z = {0.f, 0.f, 0.f, 0.f}; acc[i] = z; }

    for (int p = 0; p < NP; ++p) {
        int k0 = p * 64;
        for (int r = wid; r < 64; r += 4) {
            int gr = row0 + r;
            int kk = k0 + lane;
            float v = (gr < M && kk < K) ? A[(size_t)gr * K + kk] : 0.f;
            As[r * 72 + lane] = f2bf(v);
        }
        for (int r = wid; r < N; r += 4)
            Ws[r * 72 + lane] = Wt[(size_t)r * KPAD + k0 + lane];
        __syncthreads();
#pragma unroll
        for (int c2 = 0; c2 < 2; ++c2) {
            int ko = c2 * 32 + quad * 8;
            bf8v af = *(const bf8v*)&As[(wid * 16 + col) * 72 + ko];
#pragma unroll
            for (int nt = 0; nt < NT; ++nt) {
                bf8v bf = *(const bf8v*)&Ws[(nt * 16 + col) * 72 + ko];
                acc[nt] = __builtin_amdgcn_mfma_f32_16x16x32_bf16(af, bf, acc[nt], 0, 0, 0);
            }
        }
        __syncthreads();
    }

    int mbase = row0 + wid * 16;
    if constexpr (STORE_C) {
#pragma unroll
        for (int nt = 0; nt < NT; ++nt)
#pragma unroll
            for (int r = 0; r < 4; ++r) {
                int gr = mbase + quad * 4 + r;
                if (gr < M) C[(size_t)gr * N + nt * 16 + col] = acc[nt][r];
            }
    }
    if constexpr (DO_F) {
        float a0[NT], a1[NT];
#pragma unroll
        for (int nt = 0; nt < NT; ++nt) {
            a0[nt] = av[nt * 16 + col];
            a1[nt] = av[N + nt * 16 + col];
        }
#pragma unroll
        for (int r = 0; r < 4; ++r) {
            float p0 = 0.f, p1 = 0.f;
#pragma unroll
            for (int nt = 0; nt < NT; ++nt) {
                p0 += acc[nt][r] * a0[nt];
                p1 += acc[nt][r] * a1[nt];
            }
#pragma unroll
            for (int o = 8; o > 0; o >>= 1) {
                p0 += __shfl_xor(p0, o, 64);
                p1 += __shfl_xor(p1, o, 64);
            }
            int gr = mbase + quad * 4 + r;
            if (col == 0 && gr < M) { fs[gr] = p0; fd[gr] = p1; }
        }
    }
    if constexpr (DO_ATT) {
        float s = 0.f;
#pragma unroll
        for (int nt = 0; nt < NT; ++nt) {
            float pj = av[nt * 16 + col];
#pragma unroll
            for (int r = 0; r < 4; ++r) s += tanhf(acc[nt][r]) * pj;
        }
        s = waveReduce(s);
        if (lane == 0) red[wid] = s;
        __syncthreads();
        if (t == 0) atomicAdd(attsum, red[0] + red[1] + red[2] + red[3]);
    }
}

// h[i,:] = mean_16 P[idx[i,j],:]; fused fs=h.a[:64], fd=h.a[64:128]
__global__ void gather_h64(const int* __restrict__ idx, const float* __restrict__ P,
                           const float* __restrict__ a,
                           float* __restrict__ H, float* __restrict__ fs, float* __restrict__ fd,
                           int N) {
    int wv = (blockIdx.x * blockDim.x + threadIdx.x) >> 6;
    int lane = threadIdx.x & 63;
    if (wv >= N) return;
    const int* ip = idx + wv * 16;
    int inds[16];
#pragma unroll
    for (int j = 0; j < 16; ++j) inds[j] = ip[j];
    float acc = 0.f;
#pragma unroll
    for (int j = 0; j < 16; ++j) acc += P[(size_t)inds[j] * 64 + lane];
    acc *= 0.0625f;
    H[(size_t)wv * 64 + lane] = acc;
    float p = waveReduce(acc * a[lane]);
    float q = waveReduce(acc * a[64 + lane]);
    if (lane == 0) { fs[wv] = p; fd[wv] = q; }
}

// ---------------- CSR build ----------------
__global__ void zero_int_kernel(int* p, int n) {
    int i = blockIdx.x * blockDim.x + threadIdx.x;
    if (i < n) p[i] = 0;
}

__global__ void count_kernel(const int* __restrict__ row, int* __restrict__ deg, int E) {
    int i = blockIdx.x * blockDim.x + threadIdx.x;
    if (i < E) atomicAdd(&deg[row[i]], 1);
}

// hierarchical scan: part sums -> offsets -> block-local exclusive write
#define SCAN_BS 256
#define SCAN_CHUNK 1024   // 4 elements/thread

__global__ __launch_bounds__(SCAN_BS) void scan_part_kernel(const int* __restrict__ deg,
                                                            int* __restrict__ part, int N) {
    __shared__ int s[SCAN_BS];
    int b = blockIdx.x, t = threadIdx.x;
    int base = b * SCAN_CHUNK + t * 4;
    int sum = 0;
#pragma unroll
    for (int j = 0; j < 4; ++j) { int i = base + j; if (i < N) sum += deg[i]; }
    s[t] = sum;
    __syncthreads();
    for (int o = SCAN_BS / 2; o > 0; o >>= 1) {
        if (t < o) s[t] += s[t + o];
        __syncthreads();
    }
    if (t == 0) part[b] = s[0];
}

// one block; nb <= 1024; writes exclusive offsets + total into rowptrN
__global__ __launch_bounds__(1024) void scan_offs_kernel(const int* __restrict__ part,
                                                         int* __restrict__ offs,
                                                         int* __restrict__ rowptrN, int nb) {
    __shared__ int s[1024];
    int t = threadIdx.x;
    s[t] = (t < nb) ? part[t] : 0;
    __syncthreads();
    for (int o = 1; o < 1024; o <<= 1) {
        int v = (t >= o) ? s[t - o] : 0;
        __syncthreads();
        s[t] += v;
        __syncthreads();
    }
    if (t < nb) offs[t] = (t == 0) ? 0 : s[t - 1];
    if (t == nb - 1) *rowptrN = s[t];
}

__global__ __launch_bounds__(SCAN_BS) void scan_write_kernel(const int* __restrict__ deg,
                                                             const int* __restrict__ offs,
                                                             int* __restrict__ rowptr,
                                                             int* __restrict__ cursor, int N) {
    __shared__ int s[SCAN_BS];
    int b = blockIdx.x, t = threadIdx.x;
    int base = b * SCAN_CHUNK + t * 4;
    int v[4];
    int sum = 0;
#pragma unroll
    for (int j = 0; j < 4; ++j) {
        int i = base + j;
        v[j] = (i < N) ? deg[i] : 0;
        sum += v[j];
    }
    s[t] = sum;
    __syncthreads();
    for (int o = 1; o < SCAN_BS; o <<= 1) {
        int y = (t >= o) ? s[t - o] : 0;
        __syncthreads();
        s[t] += y;
        __syncthreads();
    }
    int run = offs[b] + s[t] - sum;   // exclusive thread offset
#pragma unroll
    for (int j = 0; j < 4; ++j) {
        int i = base + j;
        if (i < N) { rowptr[i] = run; cursor[i] = run; run += v[j]; }
    }
}

__global__ void scatter_kernel(const int* __restrict__ row, const int* __restrict__ col,
                               int* __restrict__ cursor, int* __restrict__ ecol, int E) {
    int i = blockIdx.x * blockDim.x + threadIdx.x;
    if (i >= E) return;
    int p = atomicAdd(&cursor[row[i]], 1);
    ecol[p] = col[i];
}

// ---------------- CSR aggregation ----------------
__global__ void agg64_kernel(const int* __restrict__ rowptr, const int* __restrict__ ecol,
                             const float* __restrict__ fs, const float* __restrict__ fd,
                             const float* __restrict__ h, float* __restrict__ out, int N) {
    int wv = (blockIdx.x * blockDim.x + threadIdx.x) >> 6;
    int lane = threadIdx.x & 63;
    if (wv >= N) return;
    int s = rowptr[wv], en = rowptr[wv + 1];
    float fsr = fs[wv];
    float acc0 = 0.f, acc1 = 0.f, den = 0.f;
    int j = s;
    for (; j + 1 < en; j += 2) {
        int c0 = ecol[j], c1 = ecol[j + 1];
        float f0 = fsr + fd[c0], f1 = fsr + fd[c1];
        float e0 = expf(-(f0 >= 0.f ? f0 : 0.2f * f0));
        float e1 = expf(-(f1 >= 0.f ? f1 : 0.2f * f1));
        acc0 += e0 * h[(size_t)c0 * 64 + lane];
        acc1 += e1 * h[(size_t)c1 * 64 + lane];
        den += e0 + e1;
    }
    if (j < en) {
        int c = ecol[j];
        float f = fsr + fd[c];
        float e = expf(-(f >= 0.f ? f : 0.2f * f));
        acc0 += e * h[(size_t)c * 64 + lane];
        den += e;
    }
    float v = (acc0 + acc1) / (den + 1e-16f);
    out[(size_t)wv * 64 + lane] = v > 0.f ? v : expm1f(v);
}

__global__ void agg128_kernel(const int* __restrict__ rowptr, const int* __restrict__ ecol,
                              const float* __restrict__ fs, const float* __restrict__ fd,
                              const float2* __restrict__ h, float2* __restrict__ out, int N) {
    int wv = (blockIdx.x * blockDim.x + threadIdx.x) >> 6;
    int lane = threadIdx.x & 63;
    if (wv >= N) return;
    int s = rowptr[wv], en = rowptr[wv + 1];
    float fsr = fs[wv];
    float ax = 0.f, ay = 0.f, bx = 0.f, by = 0.f, den = 0.f;
    int j = s;
    for (; j + 1 < en; j += 2) {
        int c0 = ecol[j], c1 = ecol[j + 1];
        float f0 = fsr + fd[c0], f1 = fsr + fd[c1];
        float e0 = expf(-(f0 >= 0.f ? f0 : 0.2f * f0));
        float e1 = expf(-(f1 >= 0.f ? f1 : 0.2f * f1));
        float2 v0 = h[(size_t)c0 * 64 + lane];
        float2 v1 = h[(size_t)c1 * 64 + lane];
        ax += e0 * v0.x; ay += e0 * v0.y;
        bx += e1 * v1.x; by += e1 * v1.y;
        den += e0 + e1;
    }
    if (j < en) {
        int c = ecol[j];
        float f = fsr + fd[c];
        float e = expf(-(f >= 0.f ? f : 0.2f * f));
        float2 v = h[(size_t)c * 64 + lane];
        ax += e * v.x; ay += e * v.y;
        den += e;
    }
    float inv = 1.0f / (den + 1e-16f);
    float vx = (ax + bx) * inv, vy = (ay + by) * inv;
    float2 o;
    o.x = vx > 0.f ? vx : expm1f(vx);
    o.y = vy > 0.f ? vy : expm1f(vy);
    out[(size_t)wv * 64 + lane] = o;
}

// ---------------- output ----------------
__global__ void final_kernel(const float* __restrict__ twX, const float* __restrict__ tuX,
                             const int* __restrict__ twi, const int* __restrict__ tui,
                             const float* __restrict__ attsum,
                             const float* __restrict__ outW, const float* __restrict__ outb,
                             float* __restrict__ out, int B, float invNtw, float invNuv) {
    int wave = (blockIdx.x * blockDim.x + threadIdx.x) >> 6;
    int lane = threadIdx.x & 63;
    if (wave >= B) return;
    float z0 = attsum[0] * invNtw, z1 = attsum[1] * invNuv;
    float m = fmaxf(z0, z1);
    float e0 = expf(z0 - m), e1 = expf(z1 - m);
    float a0 = e0 / (e0 + e1), a1 = e1 / (e0 + e1);
    int ti = twi[wave], ui = tui[wave];
    float l0 = 0.f, l1 = 0.f;
#pragma unroll
    for (int p = 0; p < 2; ++p) {
        int j = lane + 64 * p;
        float feat = a0 * twX[(size_t)ti * 128 + j] + a1 * tuX[(size_t)ui * 128 + j];
        l0 += feat * outW[j];
        l1 += feat * outW[128 + j];
    }
    l0 = waveReduce(l0);
    l1 = waveReduce(l1);
    if (lane == 0) {
        l0 += outb[0];
        l1 += outb[1];
        float mm = fmaxf(l0, l1);
        float lse = mm + logf(expf(l0 - mm) + expf(l1 - mm));
        out[wave * 2 + 0] = l0 - lse;
        out[wave * 2 + 1] = l1 - lse;
    }
}

extern "C" void kernel_launch(void* const* d_in, const int* in_sizes, int n_in,
                              void* d_out, int out_size, void* d_ws, size_t ws_size,
                              hipStream_t stream) {
    const int* features_index = (const int*)d_in[0];
    const int* tw_edges = (const int*)d_in[1];
    const int* ut_edges = (const int*)d_in[2];
    const int* tw_gidx = (const int*)d_in[3];
    const int* ut_gidx = (const int*)d_in[4];
    const float* word_emb = (const float*)d_in[5];
    const float* user_emb = (const float*)d_in[6];
    const float* tw_W1 = (const float*)d_in[7];
    const float* tw_a1 = (const float*)d_in[8];
    const float* tw_W2 = (const float*)d_in[9];
    const float* tw_a2 = (const float*)d_in[10];
    const float* tu_W1 = (const float*)d_in[11];
    const float* tu_a1 = (const float*)d_in[12];
    const float* tu_W2 = (const float*)d_in[13];
    const float* tu_a2 = (const float*)d_in[14];
    const float* weight_W = (const float*)d_in[15];
    const float* weight_proj = (const float*)d_in[16];
    const float* out_W = (const float*)d_in[17];
    const float* out_b = (const float*)d_in[18];

    const int E = in_sizes[1] / 2;              // 800000
    const int NTW = in_sizes[0] / 16;           // 50000
    const int VOCAB = in_sizes[5] / 300;        // 50000
    const int UV = in_sizes[6] / 300;           // 50000
    const int B = in_sizes[3];                  // 4096
    const int Nmax = NTW > UV ? NTW : UV;
    const int Pmax = VOCAB > Nmax ? VOCAB : Nmax;

    char* ws = (char*)d_ws;
    size_t off = 0;
    auto carve = [&](size_t bytes) -> void* {
        void* p = ws + off;
        off += (bytes + 255) & ~(size_t)255;
        return p;
    };
    float* Pbuf = (float*)carve((size_t)Pmax * 64 * sizeof(float));
    float* bufH = (float*)carve((size_t)Nmax * 128 * sizeof(float));
    float* num1 = (float*)carve((size_t)Nmax * 64 * sizeof(float));
    float* twXf = (float*)carve((size_t)NTW * 128 * sizeof(float));
    float* tuXf = (float*)carve((size_t)UV * 128 * sizeof(float));
    float* f_s = (float*)carve((size_t)Nmax * sizeof(float));
    float* f_d = (float*)carve((size_t)Nmax * sizeof(float));
    float* attsum = (float*)carve(256);
    int* deg = (int*)carve((size_t)Nmax * sizeof(int));
    int* rowptr = (int*)carve((size_t)(Nmax + 1) * sizeof(int));
    int* cursor = (int*)carve((size_t)Nmax * sizeof(int));
    int* ecol = (int*)carve((size_t)E * sizeof(int));
    int* part = (int*)carve(1024 * sizeof(int));
    int* offs = (int*)carve(1024 * sizeof(int));
    short* Wt1tw = (short*)carve((size_t)64 * 320 * sizeof(short));
    short* Wt1tu = (short*)carve((size_t)64 * 320 * sizeof(short));
    short* Wt2tw = (short*)carve((size_t)128 * 64 * sizeof(short));
    short* Wt2tu = (short*)carve((size_t)128 * 64 * sizeof(short));
    short* Wta   = (short*)carve((size_t)128 * 128 * sizeof(short));
    (void)ws_size; (void)n_in; (void)out_size;

    int gE = (E + 255) / 256;

    wtrans_kernel<<<(64 * 320 + 255) / 256, 256, 0, stream>>>(tw_W1, Wt1tw, 300, 64, 320);
    wtrans_kernel<<<(64 * 320 + 255) / 256, 256, 0, stream>>>(tu_W1, Wt1tu, 300, 64, 320);
    wtrans_kernel<<<(128 * 64 + 255) / 256, 256, 0, stream>>>(tw_W2, Wt2tw, 64, 128, 64);
    wtrans_kernel<<<(128 * 64 + 255) / 256, 256, 0, stream>>>(tu_W2, Wt2tu, 64, 128, 64);
    wtrans_kernel<<<(128 * 128 + 255) / 256, 256, 0, stream>>>(weight_W, Wta, 128, 128, 128);

    auto build_csr = [&](const int* row, const int* col, int N) {
        int nb = (N + SCAN_CHUNK - 1) / SCAN_CHUNK;
        zero_int_kernel<<<(N + 255) / 256, 256, 0, stream>>>(deg, N);
        count_kernel<<<gE, 256, 0, stream>>>(row, deg, E);
        scan_part_kernel<<<nb, SCAN_BS, 0, stream>>>(deg, part, N);
        scan_offs_kernel<<<1, 1024, 0, stream>>>(part, offs, rowptr + N, nb);
        scan_write_kernel<<<nb, SCAN_BS, 0, stream>>>(deg, offs, rowptr, cursor, N);
        scatter_kernel<<<gE, 256, 0, stream>>>(row, col, cursor, ecol, E);
    };

    // ================= tweet branch =================
    {
        int N = NTW;
        build_csr(tw_edges, tw_edges + E, N);
        mfma_gemm<300, 320, 64, true, false, false><<<(VOCAB + 63) / 64, 256, 0, stream>>>(
            word_emb, Wt1tw, nullptr, Pbuf, nullptr, nullptr, nullptr, VOCAB);
        gather_h64<<<(N + 3) / 4, 256, 0, stream>>>(features_index, Pbuf, tw_a1,
                                                    bufH, f_s, f_d, N);
        agg64_kernel<<<(N + 3) / 4, 256, 0, stream>>>(rowptr, ecol, f_s, f_d, bufH, num1, N);
        mfma_gemm<64, 64, 128, true, true, false><<<(N + 63) / 64, 256, 0, stream>>>(
            num1, Wt2tw, tw_a2, bufH, f_s, f_d, nullptr, N);
        agg128_kernel<<<(N + 3) / 4, 256, 0, stream>>>(rowptr, ecol, f_s, f_d,
                                                       (const float2*)bufH, (float2*)twXf, N);
    }
    // ================= user branch =================
    {
        int N = UV;
        build_csr(ut_edges, ut_edges + E, N);
        mfma_gemm<300, 320, 64, true, true, false><<<(N + 63) / 64, 256, 0, stream>>>(
            user_emb, Wt1tu, tu_a1, bufH, f_s, f_d, nullptr, N);
        agg64_kernel<<<(N + 3) / 4, 256, 0, stream>>>(rowptr, ecol, f_s, f_d, bufH, num1, N);
        mfma_gemm<64, 64, 128, true, true, false><<<(N + 63) / 64, 256, 0, stream>>>(
            num1, Wt2tu, tu_a2, bufH, f_s, f_d, nullptr, N);
        agg128_kernel<<<(N + 3) / 4, 256, 0, stream>>>(rowptr, ecol, f_s, f_d,
                                                       (const float2*)bufH, (float2*)tuXf, N);
    }

    hipMemsetAsync(attsum, 0, 2 * sizeof(float), stream);
    mfma_gemm<128, 128, 128, false, false, true><<<(NTW + 63) / 64, 256, 0, stream>>>(
        twXf, Wta, weight_proj, nullptr, nullptr, nullptr, attsum + 0, NTW);
    mfma_gemm<128, 128, 128, false, false, true><<<(UV + 63) / 64, 256, 0, stream>>>(
        tuXf, Wta, weight_proj, nullptr, nullptr, nullptr, attsum + 1, UV);

    final_kernel<<<(B + 3) / 4, 256, 0, stream>>>(twXf, tuXf, tw_gidx, ut_gidx, attsum,
                                                  out_W, out_b, (float*)d_out, B,
                                                  1.0f / (float)NTW, 1.0f / (float)UV);
}

// Round 12
// 679.446 us; speedup vs baseline: 5.3350x; 1.1812x over previous
//
#include <hip/hip_runtime.h>
#include <hip/hip_bf16.h>

typedef __hip_bfloat16 bf16;
typedef unsigned int uint32;
typedef __attribute__((ext_vector_type(8))) short s8v;   // 8 bf16 (16B)
typedef __attribute__((ext_vector_type(4))) short s4v;   // 4 bf16 (8B)
typedef __attribute__((ext_vector_type(8))) short bf8v;  // MFMA A/B frag
typedef __attribute__((ext_vector_type(4))) float f4v;   // MFMA accumulator

__device__ __forceinline__ float waveReduce(float v) {
#pragma unroll
    for (int o = 32; o > 0; o >>= 1) v += __shfl_xor(v, o, 64);
    return v;
}

__device__ __forceinline__ short f2bf(float x) {
    __hip_bfloat16 h = __float2bfloat16(x);
    return *reinterpret_cast<short*>(&h);
}
__device__ __forceinline__ float bf2f(short s) {
    return __uint_as_float(((uint32)(unsigned short)s) << 16);
}
__device__ __forceinline__ uint32 pack2(float x, float y) {
    return (uint32)(unsigned short)f2bf(x) | (((uint32)(unsigned short)f2bf(y)) << 16);
}

// ---------------- batched weight transpose: W[K,N] fp32 -> Wt[N,KPAD] bf16 ----------------
struct WJobs {
    const float* src[5];
    short* dst[5];
    int K[5], N[5], KP[5], total[5];
};
__global__ void wtrans_all(WJobs jb) {
    int j = blockIdx.y;
    int i = blockIdx.x * blockDim.x + threadIdx.x;
    if (i >= jb.total[j]) return;
    int KP = jb.KP[j];
    int n = i / KP, k = i - n * KP;
    jb.dst[j][i] = f2bf(k < jb.K[j] ? jb.src[j][(size_t)k * jb.N[j] + n] : 0.f);
}

// ---------------- universal MFMA GEMM ----------------
// AT: float (fp32 A, converted) or short (bf16 A, copied). CSTORE: 0 none, 1 fp32, 2 bf16.
template <typename AT, int K, int KPAD, int N, int CSTORE, bool DO_F, bool DO_ATT>
__global__ __launch_bounds__(256) void mfma_gemm(const AT* __restrict__ A,
                                                 const short* __restrict__ Wt,
                                                 const float* __restrict__ av,
                                                 void* __restrict__ Cv,
                                                 float* __restrict__ fs, float* __restrict__ fd,
                                                 float* __restrict__ attsum, int M) {
    constexpr int NT = N / 16;
    constexpr int NP = KPAD / 64;
    __shared__ short As[64 * 72];
    __shared__ short Ws[N * 72];
    __shared__ float red[4];
    int t = threadIdx.x;
    int lane = t & 63;
    int wid = t >> 6;
    int col = lane & 15;
    int quad = lane >> 4;
    int row0 = blockIdx.x * 64;

    f4v acc[NT];
#pragma unroll
    for (int i = 0; i < NT; ++i) { f4v z = {0.f, 0.f, 0.f, 0.f}; acc[i] = z; }

    for (int p = 0; p < NP; ++p) {
        int k0 = p * 64;
        if constexpr (sizeof(AT) == 4) {   // fp32 A: float4 loads + convert
            const float4* A4 = (const float4*)A;
            int f = t & 15, r0 = t >> 4;
#pragma unroll
            for (int r = r0; r < 64; r += 16) {
                int gr = row0 + r;
                int f4i = (k0 >> 2) + f;
                float4 v = {0.f, 0.f, 0.f, 0.f};
                if (gr < M && f4i < K / 4) v = A4[(size_t)gr * (K / 4) + f4i];
                s4v sv = {f2bf(v.x), f2bf(v.y), f2bf(v.z), f2bf(v.w)};
                *(s4v*)&As[r * 72 + f * 4] = sv;
            }
        } else {                            // bf16 A: 16B copies
            int c8 = t & 7, r0 = t >> 3;
#pragma unroll
            for (int r = r0; r < 64; r += 32) {
                int gr = row0 + r;
                s8v v = {0, 0, 0, 0, 0, 0, 0, 0};
                if (gr < M) v = *(const s8v*)&A[(size_t)gr * K + k0 + c8 * 8];
                *(s8v*)&As[r * 72 + c8 * 8] = v;
            }
        }
        {
            int c8 = t & 7, r0 = t >> 3;
#pragma unroll
            for (int r = r0; r < N; r += 32)
                *(s8v*)&Ws[r * 72 + c8 * 8] = *(const s8v*)&Wt[(size_t)r * KPAD + k0 + c8 * 8];
        }
        __syncthreads();
#pragma unroll
        for (int c2 = 0; c2 < 2; ++c2) {
            int ko = c2 * 32 + quad * 8;
            bf8v af = *(const bf8v*)&As[(wid * 16 + col) * 72 + ko];
#pragma unroll
            for (int nt = 0; nt < NT; ++nt) {
                bf8v bf = *(const bf8v*)&Ws[(nt * 16 + col) * 72 + ko];
                acc[nt] = __builtin_amdgcn_mfma_f32_16x16x32_bf16(af, bf, acc[nt], 0, 0, 0);
            }
        }
        __syncthreads();
    }

    int mbase = row0 + wid * 16;
    if constexpr (CSTORE == 1) {
        float* C = (float*)Cv;
#pragma unroll
        for (int nt = 0; nt < NT; ++nt)
#pragma unroll
            for (int r = 0; r < 4; ++r) {
                int gr = mbase + quad * 4 + r;
                if (gr < M) C[(size_t)gr * N + nt * 16 + col] = acc[nt][r];
            }
    } else if constexpr (CSTORE == 2) {
        short* C = (short*)Cv;
#pragma unroll
        for (int nt = 0; nt < NT; ++nt)
#pragma unroll
            for (int r = 0; r < 4; ++r) {
                int gr = mbase + quad * 4 + r;
                if (gr < M) C[(size_t)gr * N + nt * 16 + col] = f2bf(acc[nt][r]);
            }
    }
    if constexpr (DO_F) {
        float a0[NT], a1[NT];
#pragma unroll
        for (int nt = 0; nt < NT; ++nt) {
            a0[nt] = av[nt * 16 + col];
            a1[nt] = av[N + nt * 16 + col];
        }
#pragma unroll
        for (int r = 0; r < 4; ++r) {
            float p0 = 0.f, p1 = 0.f;
#pragma unroll
            for (int nt = 0; nt < NT; ++nt) {
                p0 += acc[nt][r] * a0[nt];
                p1 += acc[nt][r] * a1[nt];
            }
#pragma unroll
            for (int o = 8; o > 0; o >>= 1) {
                p0 += __shfl_xor(p0, o, 64);
                p1 += __shfl_xor(p1, o, 64);
            }
            int gr = mbase + quad * 4 + r;
            if (col == 0 && gr < M) { fs[gr] = p0; fd[gr] = p1; }
        }
    }
    if constexpr (DO_ATT) {
        float s = 0.f;
#pragma unroll
        for (int nt = 0; nt < NT; ++nt) {
            float pj = av[nt * 16 + col];
#pragma unroll
            for (int r = 0; r < 4; ++r) s += tanhf(acc[nt][r]) * pj;
        }
        s = waveReduce(s);
        if (lane == 0) red[wid] = s;
        __syncthreads();
        if (t == 0) atomicAdd(attsum, red[0] + red[1] + red[2] + red[3]);
    }
}

// h[i,:] = mean_16 P[idx[i,j],:] (P fp32) -> H bf16; fused fs/fd
__global__ void gather_h64(const int* __restrict__ idx, const float* __restrict__ P,
                           const float* __restrict__ a,
                           short* __restrict__ H, float* __restrict__ fs, float* __restrict__ fd,
                           int N) {
    int wv = (blockIdx.x * blockDim.x + threadIdx.x) >> 6;
    int lane = threadIdx.x & 63;
    if (wv >= N) return;
    const int* ip = idx + wv * 16;
    int inds[16];
#pragma unroll
    for (int j = 0; j < 16; ++j) inds[j] = ip[j];
    float acc = 0.f;
#pragma unroll
    for (int j = 0; j < 16; ++j) acc += P[(size_t)inds[j] * 64 + lane];
    acc *= 0.0625f;
    H[(size_t)wv * 64 + lane] = f2bf(acc);
    float p = waveReduce(acc * a[lane]);
    float q = waveReduce(acc * a[64 + lane]);
    if (lane == 0) { fs[wv] = p; fd[wv] = q; }
}

// ---------------- CSR build (both branches fused; branch B rows offset by N) ----------------
__global__ void count2_kernel(const int* __restrict__ rowA, const int* __restrict__ rowB,
                              int* __restrict__ deg, int E, int N) {
    int i = blockIdx.x * blockDim.x + threadIdx.x;
    if (i < E) atomicAdd(&deg[rowA[i]], 1);
    else if (i < 2 * E) atomicAdd(&deg[N + rowB[i - E]], 1);
}

#define SCAN_BS 256
#define SCAN_CHUNK 1024
__global__ __launch_bounds__(SCAN_BS) void scan_part_kernel(const int* __restrict__ deg,
                                                            int* __restrict__ part, int N) {
    __shared__ int s[SCAN_BS];
    int b = blockIdx.x, t = threadIdx.x;
    int base = b * SCAN_CHUNK + t * 4;
    int sum = 0;
#pragma unroll
    for (int j = 0; j < 4; ++j) { int i = base + j; if (i < N) sum += deg[i]; }
    s[t] = sum;
    __syncthreads();
    for (int o = SCAN_BS / 2; o > 0; o >>= 1) {
        if (t < o) s[t] += s[t + o];
        __syncthreads();
    }
    if (t == 0) part[b] = s[0];
}

__global__ __launch_bounds__(1024) void scan_offs_kernel(const int* __restrict__ part,
                                                         int* __restrict__ offs,
                                                         int* __restrict__ rowptrN, int nb) {
    __shared__ int s[1024];
    int t = threadIdx.x;
    s[t] = (t < nb) ? part[t] : 0;
    __syncthreads();
    for (int o = 1; o < 1024; o <<= 1) {
        int v = (t >= o) ? s[t - o] : 0;
        __syncthreads();
        s[t] += v;
        __syncthreads();
    }
    if (t < nb) offs[t] = (t == 0) ? 0 : s[t - 1];
    if (t == nb - 1) *rowptrN = s[t];
}

__global__ __launch_bounds__(SCAN_BS) void scan_write_kernel(const int* __restrict__ deg,
                                                             const int* __restrict__ offs,
                                                             int* __restrict__ rowptr,
                                                             int* __restrict__ cursor, int N) {
    __shared__ int s[SCAN_BS];
    int b = blockIdx.x, t = threadIdx.x;
    int base = b * SCAN_CHUNK + t * 4;
    int v[4];
    int sum = 0;
#pragma unroll
    for (int j = 0; j < 4; ++j) {
        int i = base + j;
        v[j] = (i < N) ? deg[i] : 0;
        sum += v[j];
    }
    s[t] = sum;
    __syncthreads();
    for (int o = 1; o < SCAN_BS; o <<= 1) {
        int y = (t >= o) ? s[t - o] : 0;
        __syncthreads();
        s[t] += y;
        __syncthreads();
    }
    int run = offs[b] + s[t] - sum;
#pragma unroll
    for (int j = 0; j < 4; ++j) {
        int i = base + j;
        if (i < N) { rowptr[i] = run; cursor[i] = run; run += v[j]; }
    }
}

__global__ void scatter2_kernel(const int* __restrict__ rowA, const int* __restrict__ colA,
                                const int* __restrict__ rowB, const int* __restrict__ colB,
                                int* __restrict__ cursor, int* __restrict__ ecol,
                                int* __restrict__ erow, int E, int N) {
    int i = blockIdx.x * blockDim.x + threadIdx.x;
    if (i < E) {
        int r = rowA[i];
        int p = atomicAdd(&cursor[r], 1);
        ecol[p] = colA[i];
        erow[p] = r;
    } else if (i < 2 * E) {
        int r = rowB[i - E];
        int p = atomicAdd(&cursor[N + r], 1);
        ecol[p] = colB[i - E];
        erow[p] = r;
    }
}

// per-edge attention weight for one layer: ev[p] = exp(-leakyrelu(fs[erow]+fd[ecol]))
__global__ void edge_e_kernel(const int* __restrict__ erow, const int* __restrict__ ecol,
                              const float* __restrict__ fs, const float* __restrict__ fd,
                              float* __restrict__ ev, int e0, int e1) {
    int i = e0 + blockIdx.x * blockDim.x + threadIdx.x;
    if (i >= e1) return;
    float f = fs[erow[i]] + fd[ecol[i]];
    ev[i] = expf(-(f >= 0.f ? f : 0.2f * f));
}

// ---------------- CSR aggregation, bf16 h, precomputed e ----------------
// h rows 64 bf16 (32 uints); two edges per iteration across wave halves
__global__ void agg64_kernel(const int* __restrict__ rowptr, const int* __restrict__ ecol,
                             const float* __restrict__ ev, const uint32* __restrict__ hb,
                             uint32* __restrict__ out, int N) {
    int wv = (blockIdx.x * blockDim.x + threadIdx.x) >> 6;
    int lane = threadIdx.x & 63;
    if (wv >= N) return;
    int s = rowptr[wv], en = rowptr[wv + 1];
    int half = lane >> 5, li = lane & 31;
    float ax = 0.f, ay = 0.f, den = 0.f;
    for (int j = s; j < en; j += 2) {
        int jj = j + half;
        if (jj < en) {
            int c = ecol[jj];
            float e = ev[jj];
            uint32 d = hb[(size_t)c * 32 + li];
            ax += e * __uint_as_float(d << 16);
            ay += e * __uint_as_float(d & 0xffff0000u);
            den += e;
        }
    }
    ax += __shfl_xor(ax, 32, 64);
    ay += __shfl_xor(ay, 32, 64);
    den += __shfl_xor(den, 32, 64);
    if (half == 0) {
        float inv = 1.f / (den + 1e-16f);
        float v0 = ax * inv, v1 = ay * inv;
        v0 = v0 > 0.f ? v0 : expm1f(v0);
        v1 = v1 > 0.f ? v1 : expm1f(v1);
        out[(size_t)wv * 32 + li] = pack2(v0, v1);
    }
}

// h rows 128 bf16 (64 uints); unrolled 2 edges
__global__ void agg128_kernel(const int* __restrict__ rowptr, const int* __restrict__ ecol,
                              const float* __restrict__ ev, const uint32* __restrict__ hb,
                              uint32* __restrict__ out, int N) {
    int wv = (blockIdx.x * blockDim.x + threadIdx.x) >> 6;
    int lane = threadIdx.x & 63;
    if (wv >= N) return;
    int s = rowptr[wv], en = rowptr[wv + 1];
    float ax0 = 0.f, ay0 = 0.f, ax1 = 0.f, ay1 = 0.f, den = 0.f;
    int j = s;
    for (; j + 1 < en; j += 2) {
        int c0 = ecol[j], c1 = ecol[j + 1];
        float e0 = ev[j], e1 = ev[j + 1];
        uint32 d0 = hb[(size_t)c0 * 64 + lane];
        uint32 d1 = hb[(size_t)c1 * 64 + lane];
        ax0 += e0 * __uint_as_float(d0 << 16);
        ay0 += e0 * __uint_as_float(d0 & 0xffff0000u);
        ax1 += e1 * __uint_as_float(d1 << 16);
        ay1 += e1 * __uint_as_float(d1 & 0xffff0000u);
        den += e0 + e1;
    }
    if (j < en) {
        int c = ecol[j];
        float e = ev[j];
        uint32 d = hb[(size_t)c * 64 + lane];
        ax0 += e * __uint_as_float(d << 16);
        ay0 += e * __uint_as_float(d & 0xffff0000u);
        den += e;
    }
    float inv = 1.f / (den + 1e-16f);
    float v0 = (ax0 + ax1) * inv, v1 = (ay0 + ay1) * inv;
    v0 = v0 > 0.f ? v0 : expm1f(v0);
    v1 = v1 > 0.f ? v1 : expm1f(v1);
    out[(size_t)wv * 64 + lane] = pack2(v0, v1);
}

// ---------------- output (bf16 X inputs) ----------------
__global__ void final_kernel(const short* __restrict__ twX, const short* __restrict__ tuX,
                             const int* __restrict__ twi, const int* __restrict__ tui,
                             const float* __restrict__ attsum,
                             const float* __restrict__ outW, const float* __restrict__ outb,
                             float* __restrict__ out, int B, float invNtw, float invNuv) {
    int wave = (blockIdx.x * blockDim.x + threadIdx.x) >> 6;
    int lane = threadIdx.x & 63;
    if (wave >= B) return;
    float z0 = attsum[0] * invNtw, z1 = attsum[1] * invNuv;
    float m = fmaxf(z0, z1);
    float e0 = expf(z0 - m), e1 = expf(z1 - m);
    float a0 = e0 / (e0 + e1), a1 = e1 / (e0 + e1);
    int ti = twi[wave], ui = tui[wave];
    float l0 = 0.f, l1 = 0.f;
#pragma unroll
    for (int p = 0; p < 2; ++p) {
        int j = lane + 64 * p;
        float feat = a0 * bf2f(twX[(size_t)ti * 128 + j]) + a1 * bf2f(tuX[(size_t)ui * 128 + j]);
        l0 += feat * outW[j];
        l1 += feat * outW[128 + j];
    }
    l0 = waveReduce(l0);
    l1 = waveReduce(l1);
    if (lane == 0) {
        l0 += outb[0];
        l1 += outb[1];
        float mm = fmaxf(l0, l1);
        float lse = mm + logf(expf(l0 - mm) + expf(l1 - mm));
        out[wave * 2 + 0] = l0 - lse;
        out[wave * 2 + 1] = l1 - lse;
    }
}

extern "C" void kernel_launch(void* const* d_in, const int* in_sizes, int n_in,
                              void* d_out, int out_size, void* d_ws, size_t ws_size,
                              hipStream_t stream) {
    const int* features_index = (const int*)d_in[0];
    const int* tw_edges = (const int*)d_in[1];
    const int* ut_edges = (const int*)d_in[2];
    const int* tw_gidx = (const int*)d_in[3];
    const int* ut_gidx = (const int*)d_in[4];
    const float* word_emb = (const float*)d_in[5];
    const float* user_emb = (const float*)d_in[6];
    const float* tw_W1 = (const float*)d_in[7];
    const float* tw_a1 = (const float*)d_in[8];
    const float* tw_W2 = (const float*)d_in[9];
    const float* tw_a2 = (const float*)d_in[10];
    const float* tu_W1 = (const float*)d_in[11];
    const float* tu_a1 = (const float*)d_in[12];
    const float* tu_W2 = (const float*)d_in[13];
    const float* tu_a2 = (const float*)d_in[14];
    const float* weight_W = (const float*)d_in[15];
    const float* weight_proj = (const float*)d_in[16];
    const float* out_W = (const float*)d_in[17];
    const float* out_b = (const float*)d_in[18];

    const int E = in_sizes[1] / 2;              // 800000
    const int NTW = in_sizes[0] / 16;           // 50000
    const int VOCAB = in_sizes[5] / 300;        // 50000
    const int UV = in_sizes[6] / 300;           // 50000
    const int B = in_sizes[3];                  // 4096
    const int Nmax = NTW > UV ? NTW : UV;
    const int N2 = NTW + UV;

    char* ws = (char*)d_ws;
    size_t off = 0;
    auto carve = [&](size_t bytes) -> void* {
        void* p = ws + off;
        off += (bytes + 255) & ~(size_t)255;
        return p;
    };
    float* Pbuf = (float*)carve((size_t)VOCAB * 64 * sizeof(float));
    short* bufH = (short*)carve((size_t)Nmax * 128 * sizeof(short));   // bf16 h (64 or 128)
    short* num1 = (short*)carve((size_t)Nmax * 64 * sizeof(short));    // bf16
    short* twXf = (short*)carve((size_t)NTW * 128 * sizeof(short));    // bf16
    short* tuXf = (short*)carve((size_t)UV * 128 * sizeof(short));     // bf16
    float* f_s = (float*)carve((size_t)Nmax * sizeof(float));
    float* f_d = (float*)carve((size_t)Nmax * sizeof(float));
    float* attsum = (float*)carve(256);
    int* deg = (int*)carve((size_t)N2 * sizeof(int));
    int* rowptr = (int*)carve((size_t)(N2 + 1) * sizeof(int));
    int* cursor = (int*)carve((size_t)N2 * sizeof(int));
    int* ecol = (int*)carve((size_t)2 * E * sizeof(int));
    int* erow = (int*)carve((size_t)2 * E * sizeof(int));
    float* ev = (float*)carve((size_t)2 * E * sizeof(float));
    int* part = (int*)carve(1024 * sizeof(int));
    int* offs = (int*)carve(1024 * sizeof(int));
    short* Wt1tw = (short*)carve((size_t)64 * 320 * sizeof(short));
    short* Wt1tu = (short*)carve((size_t)64 * 320 * sizeof(short));
    short* Wt2tw = (short*)carve((size_t)128 * 64 * sizeof(short));
    short* Wt2tu = (short*)carve((size_t)128 * 64 * sizeof(short));
    short* Wta   = (short*)carve((size_t)128 * 128 * sizeof(short));
    (void)ws_size; (void)n_in; (void)out_size;

    // ---- batched weight transposes (1 launch) ----
    WJobs jb;
    jb.src[0] = tw_W1;    jb.dst[0] = Wt1tw; jb.K[0] = 300; jb.N[0] = 64;  jb.KP[0] = 320; jb.total[0] = 64 * 320;
    jb.src[1] = tu_W1;    jb.dst[1] = Wt1tu; jb.K[1] = 300; jb.N[1] = 64;  jb.KP[1] = 320; jb.total[1] = 64 * 320;
    jb.src[2] = tw_W2;    jb.dst[2] = Wt2tw; jb.K[2] = 64;  jb.N[2] = 128; jb.KP[2] = 64;  jb.total[2] = 128 * 64;
    jb.src[3] = tu_W2;    jb.dst[3] = Wt2tu; jb.K[3] = 64;  jb.N[3] = 128; jb.KP[3] = 64;  jb.total[3] = 128 * 64;
    jb.src[4] = weight_W; jb.dst[4] = Wta;   jb.K[4] = 128; jb.N[4] = 128; jb.KP[4] = 128; jb.total[4] = 128 * 128;
    {
        dim3 g((64 * 320 + 255) / 256, 5);
        wtrans_all<<<g, 256, 0, stream>>>(jb);
    }

    // ---- fused CSR build for both branches ----
    hipMemsetAsync(deg, 0, (size_t)N2 * sizeof(int), stream);
    int g2E = (2 * E + 255) / 256;
    count2_kernel<<<g2E, 256, 0, stream>>>(tw_edges, ut_edges, deg, E, NTW);
    int nb = (N2 + SCAN_CHUNK - 1) / SCAN_CHUNK;
    scan_part_kernel<<<nb, SCAN_BS, 0, stream>>>(deg, part, N2);
    scan_offs_kernel<<<1, 1024, 0, stream>>>(part, offs, rowptr + N2, nb);
    scan_write_kernel<<<nb, SCAN_BS, 0, stream>>>(deg, offs, rowptr, cursor, N2);
    scatter2_kernel<<<g2E, 256, 0, stream>>>(tw_edges, tw_edges + E, ut_edges, ut_edges + E,
                                             cursor, ecol, erow, E, NTW);

    int gEk = (E + 255) / 256;

    // ================= tweet branch (rowptr[0..NTW], edges [0,E)) =================
    mfma_gemm<float, 300, 320, 64, 1, false, false><<<(VOCAB + 63) / 64, 256, 0, stream>>>(
        word_emb, Wt1tw, nullptr, Pbuf, nullptr, nullptr, nullptr, VOCAB);
    gather_h64<<<(NTW + 3) / 4, 256, 0, stream>>>(features_index, Pbuf, tw_a1,
                                                  bufH, f_s, f_d, NTW);
    edge_e_kernel<<<gEk, 256, 0, stream>>>(erow, ecol, f_s, f_d, ev, 0, E);
    agg64_kernel<<<(NTW + 3) / 4, 256, 0, stream>>>(rowptr, ecol, ev, (const uint32*)bufH,
                                                    (uint32*)num1, NTW);
    mfma_gemm<short, 64, 64, 128, 2, true, false><<<(NTW + 63) / 64, 256, 0, stream>>>(
        num1, Wt2tw, tw_a2, bufH, f_s, f_d, nullptr, NTW);
    edge_e_kernel<<<gEk, 256, 0, stream>>>(erow, ecol, f_s, f_d, ev, 0, E);
    agg128_kernel<<<(NTW + 3) / 4, 256, 0, stream>>>(rowptr, ecol, ev, (const uint32*)bufH,
                                                     (uint32*)twXf, NTW);
    // ================= user branch (rowptr[NTW..N2], edges [E,2E)) =================
    mfma_gemm<float, 300, 320, 64, 2, true, false><<<(UV + 63) / 64, 256, 0, stream>>>(
        user_emb, Wt1tu, tu_a1, bufH, f_s, f_d, nullptr, UV);
    edge_e_kernel<<<gEk, 256, 0, stream>>>(erow, ecol, f_s, f_d, ev, E, 2 * E);
    agg64_kernel<<<(UV + 3) / 4, 256, 0, stream>>>(rowptr + NTW, ecol, ev, (const uint32*)bufH,
                                                   (uint32*)num1, UV);
    mfma_gemm<short, 64, 64, 128, 2, true, false><<<(UV + 63) / 64, 256, 0, stream>>>(
        num1, Wt2tu, tu_a2, bufH, f_s, f_d, nullptr, UV);
    edge_e_kernel<<<gEk, 256, 0, stream>>>(erow, ecol, f_s, f_d, ev, E, 2 * E);
    agg128_kernel<<<(UV + 3) / 4, 256, 0, stream>>>(rowptr + NTW, ecol, ev, (const uint32*)bufH,
                                                    (uint32*)tuXf, UV);

    hipMemsetAsync(attsum, 0, 2 * sizeof(float), stream);
    mfma_gemm<short, 128, 128, 128, 0, false, true><<<(NTW + 63) / 64, 256, 0, stream>>>(
        twXf, Wta, weight_proj, nullptr, nullptr, nullptr, attsum + 0, NTW);
    mfma_gemm<short, 128, 128, 128, 0, false, true><<<(UV + 63) / 64, 256, 0, stream>>>(
        tuXf, Wta, weight_proj, nullptr, nullptr, nullptr, attsum + 1, UV);

    final_kernel<<<(B + 3) / 4, 256, 0, stream>>>(twXf, tuXf, tw_gidx, ut_gidx, attsum,
                                                  out_W, out_b, (float*)d_out, B,
                                                  1.0f / (float)NTW, 1.0f / (float)UV);
}